// Round 16
// baseline (192.785 us; speedup 1.0000x reference)
//
#include <hip/hip_runtime.h>
#include <stdint.h>

#define SEQ 2048
#define DIM 1024
#define NB 4
#define MTOT (NB*SEQ)
#define QKVN (3*DIM)

typedef __attribute__((ext_vector_type(8))) short short8;
typedef __attribute__((ext_vector_type(4))) float f32x4;

__device__ __forceinline__ unsigned short f2b(float f) {
    union { float f; unsigned int u; } v; v.f = f;
    return (unsigned short)((v.u + 0x7FFFu + ((v.u >> 16) & 1u)) >> 16);
}
__device__ __forceinline__ float b2f(unsigned short u) {
    union { unsigned int i; float f; } v; v.i = ((unsigned int)u) << 16; return v.f;
}

__device__ __forceinline__ void gload_lds16(const unsigned short* g, unsigned short* l) {
    __builtin_amdgcn_global_load_lds(
        (const __attribute__((address_space(1))) void*)g,
        (__attribute__((address_space(3))) void*)l, 16, 0, 0);
}

__device__ __forceinline__ short8 ds128(unsigned addr) {
    short8 r;
    asm volatile("ds_read_b128 %0, %1" : "=v"(r) : "v"(addr));
    return r;
}

#define FENCE_BARRIER do { asm volatile("" ::: "memory"); \
    __builtin_amdgcn_s_barrier(); asm volatile("" ::: "memory"); } while (0)
#define SB __builtin_amdgcn_sched_barrier(0)

__device__ __forceinline__ int xcd_swz(int bid, int nwg) {
    if (nwg & 7) return bid;
    return (bid & 7) * (nwg >> 3) + (bid >> 3);
}

// ---------------- small memory-shape kernels ----------------

__global__ __launch_bounds__(256)
void cast_kernel(const float* __restrict__ in, unsigned short* __restrict__ out, int nchunk) {
    int i = blockIdx.x * 256 + threadIdx.x;
    if (i >= nchunk) return;
    float4 a = ((const float4*)in)[i*2];
    float4 b = ((const float4*)in)[i*2+1];
    union { unsigned short u[8]; uint4 v; } r;
    r.u[0]=f2b(a.x); r.u[1]=f2b(a.y); r.u[2]=f2b(a.z); r.u[3]=f2b(a.w);
    r.u[4]=f2b(b.x); r.u[5]=f2b(b.y); r.u[6]=f2b(b.z); r.u[7]=f2b(b.w);
    ((uint4*)out)[i] = r.v;
}

__global__ __launch_bounds__(256)
void transpose_cast3(const float* __restrict__ w0, const float* __restrict__ w1,
                     const float* __restrict__ w2, unsigned short* __restrict__ out) {
    const float* in = (blockIdx.y == 0) ? w0 : (blockIdx.y == 1) ? w1 : w2;
    unsigned short* o = out + (size_t)blockIdx.y * DIM * DIM;
    __shared__ unsigned short tile[64][66];
    int tpc = DIM >> 6;
    int tr = ((int)blockIdx.x / tpc) << 6;
    int tc = ((int)blockIdx.x % tpc) << 6;
    int t = threadIdx.x;
    #pragma unroll
    for (int i = 0; i < 16; i++) {
        int idx = t + i*256;
        int r = idx >> 6, c = idx & 63;
        tile[r][c] = f2b(in[(size_t)(tr + r)*DIM + tc + c]);
    }
    __syncthreads();
    #pragma unroll
    for (int i = 0; i < 16; i++) {
        int idx = t + i*256;
        int r = idx >> 6, c = idx & 63;
        o[(size_t)(tc + r)*DIM + tr + c] = tile[c][r];
    }
}

__global__ __launch_bounds__(256)
void transpose_b16(const unsigned short* __restrict__ in0, size_t sIn, int ldin,
                   unsigned short* __restrict__ out0, size_t sOut, int ldout, int tpc) {
    const unsigned short* in = in0 + sIn * blockIdx.y;
    unsigned short* out = out0 + sOut * blockIdx.y;
    __shared__ unsigned short tile[64][66];
    int tr = ((int)blockIdx.x / tpc) << 6;
    int tc = ((int)blockIdx.x % tpc) << 6;
    int t = threadIdx.x;
    #pragma unroll
    for (int i = 0; i < 16; i++) {
        int idx = t + i*256;
        int r = idx >> 6, c = idx & 63;
        tile[r][c] = in[(size_t)(tr + r)*ldin + tc + c];
    }
    __syncthreads();
    #pragma unroll
    for (int i = 0; i < 16; i++) {
        int idx = t + i*256;
        int r = idx >> 6, c = idx & 63;
        out[(size_t)(tc + r)*ldout + tr + c] = tile[c][r];
    }
}

__global__ __launch_bounds__(256)
void bias_concat(const float* __restrict__ bq, const float* __restrict__ bk,
                 const float* __restrict__ bv, float* __restrict__ o) {
    int i = blockIdx.x*256 + threadIdx.x;
    float v = (i < DIM) ? bq[i] : ((i < 2*DIM) ? bk[i-DIM] : bv[i-2*DIM]);
    o[i] = v;
}

// -------- 64x256 4-phase pipelined GEMM, 2 blocks/CU (r14 ledger) --------
// MODE 0: bf16(acc + aux[col])                          (QKV)
// MODE 2: bf16(exp(acc*scale)) + deterministic row-sum partials -> aux  (scores)
// MODE 3: f32(acc); A reg-staged with p = u * inv[row] transform (PV);
//         aux = psum (row sums from MODE 2, 8 partials per row)
// vmcnt ledger (MODE 3's plain A-load also counts in vmcnt — audited):
// prologue {zA,BEh0x2,BEh1x2,zB,BOh0x2}=8 -> vmcnt(3) drains zA+E.B;
// p1 +BOh1x2 (5); p2 +zA'+E2Bh0x2 (8) -> vmcnt(3) drains zB+BOh0+BOh1,
// WRITE_PA(zB) -> O.A; p3 +E2Bh1x2 (5); p4 +zB'+O2Bh0x2 (8) -> vmcnt(3)
// drains zA'+E2Bh0+E2Bh1, WRITE_PA(zA') -> E2.A. Periodic; never 0 in loop.

__device__ __forceinline__ void stageA64(const unsigned short* __restrict__ Xb, int ldx,
                                         unsigned short* dstBase, int k0,
                                         int tid, int wid) {
    int srow = tid >> 3;
    int scol = ((tid & 7) ^ (srow & 7)) << 3;
    gload_lds16(Xb + (size_t)srow*ldx + k0 + scol, dstBase + wid*512);
}

__device__ __forceinline__ void stageB(const unsigned short* __restrict__ Xb, int ldx,
                                       unsigned short* dstBase, int h, int k0,
                                       int tid, int wid) {
    int srow = tid >> 3;
    int scol = ((tid & 7) ^ (srow & 7)) << 3;
    const unsigned short* g = Xb + (size_t)(h*128 + srow)*ldx + k0 + scol;
    unsigned short* d = dstBase + h*8192 + wid*512;
    gload_lds16(g, d);
    gload_lds16(g + (size_t)64*ldx, d + 4096);
}

#define RD_A(BUF) do { _Pragma("unroll") for (int mf = 0; mf < 2; ++mf) { \
    fa[mf][0] = ds128(As0 + (BUF)*8192u + aRow + mf*2048u + c0); \
    fa[mf][1] = ds128(As0 + (BUF)*8192u + aRow + mf*2048u + c1); } } while (0)

#define RD_B(BUF, QN) do { _Pragma("unroll") for (int nf = 0; nf < 2; ++nf) { \
    fb[nf][0] = ds128(Bs0 + (BUF)*32768u + (QN)*16384u + bRow + nf*2048u + c0); \
    fb[nf][1] = ds128(Bs0 + (BUF)*32768u + (QN)*16384u + bRow + nf*2048u + c1); } } while (0)

#define MMA_PH(QN) do { \
    asm volatile("s_waitcnt lgkmcnt(0)" ::: "memory"); \
    __builtin_amdgcn_sched_barrier(0); \
    __builtin_amdgcn_s_setprio(1); \
    _Pragma("unroll") for (int mf = 0; mf < 2; ++mf) \
      _Pragma("unroll") for (int nf = 0; nf < 2; ++nf) \
        _Pragma("unroll") for (int ks = 0; ks < 2; ++ks) \
          acc[QN][mf][nf] = __builtin_amdgcn_mfma_f32_16x16x32_bf16( \
              fa[mf][ks], fb[nf][ks], acc[QN][mf][nf], 0, 0, 0); \
    __builtin_amdgcn_s_setprio(0); \
} while (0)

// transform staged u -> p and ds_write into linear A slot; payload is an
// ext_vector (short8) so clang maps it onto a VGPR quad for the asm operand.
#define WRITE_PA(ZREG, BUFBYTE) do { \
    union { uint4 v; unsigned short u[8]; } zq_; zq_.v = (ZREG); \
    union { short8 s; unsigned short u[8]; } pq_; \
    _Pragma("unroll") for (int i_ = 0; i_ < 8; ++i_) \
        pq_.u[i_] = f2b(b2f(zq_.u[i_]) * invA); \
    unsigned wa_ = As0 + (BUFBYTE) + (unsigned)tid*16u; \
    asm volatile("ds_write_b128 %0, %1" :: "v"(wa_), "v"(pq_.s) : "memory"); \
    asm volatile("s_waitcnt lgkmcnt(0)" ::: "memory"); \
    SB; \
} while (0)

template<int MODE>
__global__ __launch_bounds__(512, 2)
void gemm4p(const unsigned short* __restrict__ A, int lda, size_t sA,
            const unsigned short* __restrict__ Bt, int ldb, size_t sB,
            float* __restrict__ aux,
            void* __restrict__ Cout, int ldc, size_t sC,
            int N, int K, float scale)
{
    __shared__ __align__(16) unsigned short As[2][4096];     // 2 x 64x64 (16KB)
    __shared__ __align__(16) unsigned short Bs[2][16384];    // 2 x 256x64 (64KB)
    int nbn = N >> 8;
    int bid = xcd_swz((int)blockIdx.x, (int)gridDim.x);
    int bm = bid / nbn, bn = bid % nbn;
    int bz = blockIdx.y;
    int tid = threadIdx.x;
    int lane = tid & 63;
    int wid  = tid >> 6;
    int wm = (wid >> 2) & 1;
    int wn = wid & 3;
    int rlo = lane & 15;
    int shi = lane >> 4;
    int srow = tid >> 3;
    int scol = ((tid & 7) ^ (srow & 7)) << 3;

    unsigned As0 = (unsigned)(uintptr_t)&As[0][0];
    unsigned Bs0 = (unsigned)(uintptr_t)&Bs[0][0];
    unsigned c0 = (unsigned)(((shi     ^ rlo) & 7) * 16);
    unsigned c1 = (unsigned)((((4+shi) ^ rlo) & 7) * 16);
    unsigned aRow = (unsigned)((wm*32 + rlo) * 128);
    unsigned bRow = (unsigned)((wn*32 + rlo) * 128);

    f32x4 acc[2][2][2];
    #pragma unroll
    for (int a = 0; a < 2; a++)
        #pragma unroll
        for (int b = 0; b < 2; b++)
            #pragma unroll
            for (int c = 0; c < 2; c++)
                acc[a][b][c] = (f32x4){0.f,0.f,0.f,0.f};

    const unsigned short* Ab = A + sA*bz + (size_t)(bm*64)*lda;
    const unsigned short* Bb = Bt + sB*bz + (size_t)(bn*256)*ldb;

    // MODE 3: per-thread row scale from psum partials (8 per row), before staging
    float invA = 0.f;
    const unsigned short* gArow = Ab + (size_t)srow*lda + scol;
    if constexpr (MODE == 3) {
        const float* pp = (const float*)aux + ((size_t)bz*SEQ + bm*64 + srow)*8;
        float s = pp[0]+pp[1]+pp[2]+pp[3]+pp[4]+pp[5]+pp[6]+pp[7];
        invA = 1.0f / s;
        SB;
    }

    uint4 zA, zB;
    // prologue: {A_E, B_E.h0, B_E.h1, A_O, B_O.h0} = 8 loads; vmcnt(3)
    if constexpr (MODE == 3) { SB; zA = *(const uint4*)(gArow + 0); SB; }
    else stageA64(Ab, lda, &As[0][0], 0, tid, wid);
    stageB(Bb, ldb, &Bs[0][0], 0, 0,  tid, wid);
    stageB(Bb, ldb, &Bs[0][0], 1, 0,  tid, wid);
    if constexpr (MODE == 3) { SB; zB = *(const uint4*)(gArow + 64); SB; }
    else stageA64(Ab, lda, &As[1][0], 64, tid, wid);
    stageB(Bb, ldb, &Bs[1][0], 0, 64, tid, wid);
    SB;
    asm volatile("s_waitcnt vmcnt(3)" ::: "memory");
    if constexpr (MODE == 3) WRITE_PA(zA, 0u);        // E.A ready for p1
    FENCE_BARRIER;

    short8 fa[2][2], fb[2][2];
    int nt = K >> 6;          // even, >= 4
    int nit = nt >> 1;

    for (int it = 0; it < nit; ++it) {
        int kO  = (2*it + 1) << 6;
        int kE2 = (2*it + 2 < nt) ? (2*it + 2) << 6 : 0;
        int kO2 = (2*it + 3 < nt) ? (2*it + 3) << 6 : 0;

        // p1: reads A_E + B_E qn0; stage O.Bh1; pace; MFMA E qn0
        RD_A(0); RD_B(0, 0);
        stageB(Bb, ldb, &Bs[1][0], 1, kO, tid, wid);
        asm volatile("s_waitcnt lgkmcnt(4)" ::: "memory");
        FENCE_BARRIER; MMA_PH(0); FENCE_BARRIER;
        // p2: reads B_E qn1; stage E2.A + E2.Bh0; publish O; write O.A (M3); MFMA E qn1
        RD_B(0, 1);
        if constexpr (MODE == 3) { SB; zA = *(const uint4*)(gArow + kE2); SB; }
        else stageA64(Ab, lda, &As[0][0], kE2, tid, wid);
        stageB(Bb, ldb, &Bs[0][0], 0, kE2, tid, wid);
        SB;
        asm volatile("s_waitcnt vmcnt(3)" ::: "memory");
        if constexpr (MODE == 3) WRITE_PA(zB, 8192u);  // O.A (read at p3)
        FENCE_BARRIER; MMA_PH(1); FENCE_BARRIER;
        // p3: reads A_O + B_O qn0; stage E2.Bh1; pace; MFMA O qn0
        RD_A(1); RD_B(1, 0);
        stageB(Bb, ldb, &Bs[0][0], 1, kE2, tid, wid);
        asm volatile("s_waitcnt lgkmcnt(4)" ::: "memory");
        FENCE_BARRIER; MMA_PH(0); FENCE_BARRIER;
        // p4: reads B_O qn1; stage O2.A + O2.Bh0; publish E2; write E2.A (M3); MFMA O qn1
        RD_B(1, 1);
        if constexpr (MODE == 3) { SB; zB = *(const uint4*)(gArow + kO2); SB; }
        else stageA64(Ab, lda, &As[1][0], kO2, tid, wid);
        stageB(Bb, ldb, &Bs[1][0], 0, kO2, tid, wid);
        SB;
        asm volatile("s_waitcnt vmcnt(3)" ::: "memory");
        if constexpr (MODE == 3) WRITE_PA(zA, 0u);     // E2.A (read at next p1)
        FENCE_BARRIER; MMA_PH(1); FENCE_BARRIER;
    }

    // drain all DMAs, then block-wide barrier so LDS is quiescent
    asm volatile("s_waitcnt vmcnt(0)" ::: "memory");
    FENCE_BARRIER;

    int r0 = shi << 2;
    unsigned short* Cu = (unsigned short*)Cout + sC*bz;
    float* Cf = (float*)Cout + sC*bz;

    if constexpr (MODE == 2) {
        // write u = exp(acc*scale); accumulate per-row partial sums
        float rs[2][4];
        #pragma unroll
        for (int mf = 0; mf < 2; ++mf)
            #pragma unroll
            for (int r = 0; r < 4; ++r) rs[mf][r] = 0.f;
        #pragma unroll
        for (int qn = 0; qn < 2; ++qn)
            #pragma unroll
            for (int mf = 0; mf < 2; ++mf)
                #pragma unroll
                for (int nf = 0; nf < 2; ++nf) {
                    int col = bn*256 + qn*128 + wn*32 + nf*16 + rlo;
                    #pragma unroll
                    for (int r = 0; r < 4; ++r) {
                        int row = bm*64 + wm*32 + mf*16 + r0 + r;
                        float u = __expf(acc[qn][mf][nf][r] * scale);
                        Cu[(size_t)row*ldc + col] = f2b(u);
                        rs[mf][r] += u;
                    }
                }
        // reduce across the 16 rlo-lanes (same rows)
        #pragma unroll
        for (int m = 1; m < 16; m <<= 1)
            #pragma unroll
            for (int mf = 0; mf < 2; ++mf)
                #pragma unroll
                for (int r = 0; r < 4; ++r)
                    rs[mf][r] += __shfl_xor(rs[mf][r], m);
        // reduce across the 4 wn-waves via LDS (deterministic)
        float* redL = (float*)&As[0][0];   // [64][5]
        if (rlo == 0) {
            #pragma unroll
            for (int mf = 0; mf < 2; ++mf)
                #pragma unroll
                for (int r = 0; r < 4; ++r)
                    redL[(wm*32 + mf*16 + (shi<<2) + r)*5 + wn] = rs[mf][r];
        }
        __syncthreads();
        if (tid < 64) {
            float s = redL[tid*5+0] + redL[tid*5+1] + redL[tid*5+2] + redL[tid*5+3];
            aux[((size_t)bz*SEQ + bm*64 + tid)*8 + bn] = s;
        }
        return;
    }

    #pragma unroll
    for (int qn = 0; qn < 2; ++qn)
        #pragma unroll
        for (int mf = 0; mf < 2; ++mf)
            #pragma unroll
            for (int nf = 0; nf < 2; ++nf) {
                int col = bn*256 + qn*128 + wn*32 + nf*16 + rlo;
                float badd = (MODE == 0) ? aux[col] : 0.f;
                #pragma unroll
                for (int r = 0; r < 4; ++r) {
                    int row = bm*64 + wm*32 + mf*16 + r0 + r;
                    float v = acc[qn][mf][nf][r];
                    if (MODE == 0) Cu[(size_t)row*ldc + col] = f2b(v + badd);
                    else           Cf[(size_t)row*ldc + col] = v;
                }
            }
}

extern "C" void kernel_launch(void* const* d_in, const int* in_sizes, int n_in,
                              void* d_out, int out_size, void* d_ws, size_t ws_size,
                              hipStream_t stream)
{
    (void)in_sizes; (void)n_in; (void)out_size;
    const float* x  = (const float*)d_in[0];
    const float* Wq = (const float*)d_in[1];
    const float* bq = (const float*)d_in[2];
    const float* Wk = (const float*)d_in[3];
    const float* bk = (const float*)d_in[4];
    const float* Wv = (const float*)d_in[5];
    const float* bv = (const float*)d_in[6];
    float* out = (float*)d_out;

    unsigned short* qkv = (unsigned short*)d_ws;                    // [8192][3072]
    unsigned short* vt  = qkv + (size_t)MTOT*QKVN;                  // [4][1024][2048]
    float* biasc = (float*)(vt + (size_t)NB*DIM*SEQ);               // [3072]
    char* ovl = (char*)biasc + 65536;
    unsigned short* xb    = (unsigned short*)ovl;                   // [8192][1024]
    unsigned short* wqkvt = xb + (size_t)MTOT*DIM;                  // [3072][1024]
    unsigned short* scoresB = (unsigned short*)ovl;                 // [bpp][2048][2048] bf16

    size_t base = (size_t)MTOT*QKVN*2 + (size_t)NB*DIM*SEQ*2 + 65536;
    int bpp = 1;
    if (base + 4*((size_t)SEQ*SEQ*2 + SEQ*32) <= ws_size) bpp = 4;
    else if (base + 2*((size_t)SEQ*SEQ*2 + SEQ*32) <= ws_size) bpp = 2;
    float* psum = (float*)(scoresB + (size_t)bpp*SEQ*SEQ);          // [bpp][2048][8]

    cast_kernel<<<MTOT*DIM/8/256, 256, 0, stream>>>(x, xb, MTOT*DIM/8);
    transpose_cast3<<<dim3(256, 3), 256, 0, stream>>>(Wq, Wk, Wv, wqkvt);
    bias_concat<<<QKVN/256, 256, 0, stream>>>(bq, bk, bv, biasc);

    // fused QKV projection: grid 128x12=1536 (3.0 rounds @ 2/CU)
    gemm4p<0><<<dim3((MTOT/64)*(QKVN/256)), 512, 0, stream>>>(
        xb, DIM, 0, wqkvt, DIM, 0, biasc, qkv, QKVN, 0, QKVN, DIM, 1.f);

    transpose_b16<<<dim3((SEQ/64)*(DIM/64), NB), 256, 0, stream>>>(
        qkv + 2*DIM, (size_t)SEQ*QKVN, QKVN, vt, (size_t)DIM*SEQ, SEQ, DIM/64);

    const float scl = 1.0f / 32.0f;   // 1/sqrt(1024)
    for (int p = 0; p < NB; p += bpp) {
        const unsigned short* qp = qkv + (size_t)p*SEQ*QKVN;
        // scores: u = exp((Q.K^T)/32) bf16 + deterministic row-sum partials -> psum
        gemm4p<2><<<dim3((SEQ/64)*(SEQ/256), bpp), 512, 0, stream>>>(
            qp,       QKVN, (size_t)SEQ*QKVN,
            qp + DIM, QKVN, (size_t)SEQ*QKVN,
            psum, scoresB, SEQ, (size_t)SEQ*SEQ, SEQ, DIM, scl);
        // PV: out = (u * inv[row]) . V — p applied during A staging; no softmax kernel
        gemm4p<3><<<dim3((SEQ/64)*(DIM/256), bpp), 512, 0, stream>>>(
            scoresB, SEQ, (size_t)SEQ*SEQ,
            vt + (size_t)p*DIM*SEQ, SEQ, (size_t)DIM*SEQ,
            psum, out + (size_t)p*SEQ*DIM, DIM, (size_t)SEQ*DIM, DIM, SEQ, 1.f);
    }
}

// Round 17
// 173.139 us; speedup vs baseline: 1.1135x; 1.1135x over previous
//
#include <hip/hip_runtime.h>
#include <stdint.h>

#define SEQ 2048
#define DIM 1024
#define NB 4
#define MTOT (NB*SEQ)
#define QKVN (3*DIM)

typedef __attribute__((ext_vector_type(8))) short short8;
typedef __attribute__((ext_vector_type(4))) float f32x4;

__device__ __forceinline__ unsigned short f2b(float f) {
    union { float f; unsigned int u; } v; v.f = f;
    return (unsigned short)((v.u + 0x7FFFu + ((v.u >> 16) & 1u)) >> 16);
}
__device__ __forceinline__ float b2f(unsigned short u) {
    union { unsigned int i; float f; } v; v.i = ((unsigned int)u) << 16; return v.f;
}

__device__ __forceinline__ void gload_lds16(const unsigned short* g, unsigned short* l) {
    __builtin_amdgcn_global_load_lds(
        (const __attribute__((address_space(1))) void*)g,
        (__attribute__((address_space(3))) void*)l, 16, 0, 0);
}

__device__ __forceinline__ short8 ds128(unsigned addr) {
    short8 r;
    asm volatile("ds_read_b128 %0, %1" : "=v"(r) : "v"(addr));
    return r;
}

#define FENCE_BARRIER do { asm volatile("" ::: "memory"); \
    __builtin_amdgcn_s_barrier(); asm volatile("" ::: "memory"); } while (0)
#define SB __builtin_amdgcn_sched_barrier(0)

__device__ __forceinline__ int xcd_swz(int bid, int nwg) {
    if (nwg & 7) return bid;
    return (bid & 7) * (nwg >> 3) + (bid >> 3);
}

// ---------------- small memory-shape kernels ----------------

__global__ __launch_bounds__(256)
void cast_kernel(const float* __restrict__ in, unsigned short* __restrict__ out, int nchunk) {
    int i = blockIdx.x * 256 + threadIdx.x;
    if (i >= nchunk) return;
    float4 a = ((const float4*)in)[i*2];
    float4 b = ((const float4*)in)[i*2+1];
    union { unsigned short u[8]; uint4 v; } r;
    r.u[0]=f2b(a.x); r.u[1]=f2b(a.y); r.u[2]=f2b(a.z); r.u[3]=f2b(a.w);
    r.u[4]=f2b(b.x); r.u[5]=f2b(b.y); r.u[6]=f2b(b.z); r.u[7]=f2b(b.w);
    ((uint4*)out)[i] = r.v;
}

__global__ __launch_bounds__(256)
void transpose_cast3(const float* __restrict__ w0, const float* __restrict__ w1,
                     const float* __restrict__ w2, unsigned short* __restrict__ out) {
    const float* in = (blockIdx.y == 0) ? w0 : (blockIdx.y == 1) ? w1 : w2;
    unsigned short* o = out + (size_t)blockIdx.y * DIM * DIM;
    __shared__ unsigned short tile[64][66];
    int tpc = DIM >> 6;
    int tr = ((int)blockIdx.x / tpc) << 6;
    int tc = ((int)blockIdx.x % tpc) << 6;
    int t = threadIdx.x;
    #pragma unroll
    for (int i = 0; i < 16; i++) {
        int idx = t + i*256;
        int r = idx >> 6, c = idx & 63;
        tile[r][c] = f2b(in[(size_t)(tr + r)*DIM + tc + c]);
    }
    __syncthreads();
    #pragma unroll
    for (int i = 0; i < 16; i++) {
        int idx = t + i*256;
        int r = idx >> 6, c = idx & 63;
        o[(size_t)(tc + r)*DIM + tr + c] = tile[c][r];
    }
}

__global__ __launch_bounds__(256)
void transpose_b16(const unsigned short* __restrict__ in0, size_t sIn, int ldin,
                   unsigned short* __restrict__ out0, size_t sOut, int ldout, int tpc) {
    const unsigned short* in = in0 + sIn * blockIdx.y;
    unsigned short* out = out0 + sOut * blockIdx.y;
    __shared__ unsigned short tile[64][66];
    int tr = ((int)blockIdx.x / tpc) << 6;
    int tc = ((int)blockIdx.x % tpc) << 6;
    int t = threadIdx.x;
    #pragma unroll
    for (int i = 0; i < 16; i++) {
        int idx = t + i*256;
        int r = idx >> 6, c = idx & 63;
        tile[r][c] = in[(size_t)(tr + r)*ldin + tc + c];
    }
    __syncthreads();
    #pragma unroll
    for (int i = 0; i < 16; i++) {
        int idx = t + i*256;
        int r = idx >> 6, c = idx & 63;
        out[(size_t)(tc + r)*ldout + tr + c] = tile[c][r];
    }
}

__global__ __launch_bounds__(256)
void bias_concat(const float* __restrict__ bq, const float* __restrict__ bk,
                 const float* __restrict__ bv, float* __restrict__ o) {
    int i = blockIdx.x*256 + threadIdx.x;
    float v = (i < DIM) ? bq[i] : ((i < 2*DIM) ? bk[i-DIM] : bv[i-2*DIM]);
    o[i] = v;
}

// -------- 64x256 4-phase pipelined GEMM, 2 blocks/CU (r14 ledger, ALL modes) --------
// Main loop identical for every MODE (global_load_lds staging everywhere).
// MODE 0: bf16(acc + aux[col])                                       (QKV)
// MODE 2: bf16(exp(acc*scale)) + deterministic row-sum partials->aux (scores)
// MODE 3: f32(acc * inv[row]), inv from aux's 8 partials per row     (PV)
// vmcnt ledger: prologue 8 -> vmcnt(3); p1 +2; p2 +3, vmcnt(3) publish O;
// p3 +2; p4 +3, vmcnt(3) publish E2. Never 0 in loop.

__device__ __forceinline__ void stageA64(const unsigned short* __restrict__ Xb, int ldx,
                                         unsigned short* dstBase, int k0,
                                         int tid, int wid) {
    int srow = tid >> 3;
    int scol = ((tid & 7) ^ (srow & 7)) << 3;
    gload_lds16(Xb + (size_t)srow*ldx + k0 + scol, dstBase + wid*512);
}

__device__ __forceinline__ void stageB(const unsigned short* __restrict__ Xb, int ldx,
                                       unsigned short* dstBase, int h, int k0,
                                       int tid, int wid) {
    int srow = tid >> 3;
    int scol = ((tid & 7) ^ (srow & 7)) << 3;
    const unsigned short* g = Xb + (size_t)(h*128 + srow)*ldx + k0 + scol;
    unsigned short* d = dstBase + h*8192 + wid*512;
    gload_lds16(g, d);
    gload_lds16(g + (size_t)64*ldx, d + 4096);
}

#define RD_A(BUF) do { _Pragma("unroll") for (int mf = 0; mf < 2; ++mf) { \
    fa[mf][0] = ds128(As0 + (BUF)*8192u + aRow + mf*2048u + c0); \
    fa[mf][1] = ds128(As0 + (BUF)*8192u + aRow + mf*2048u + c1); } } while (0)

#define RD_B(BUF, QN) do { _Pragma("unroll") for (int nf = 0; nf < 2; ++nf) { \
    fb[nf][0] = ds128(Bs0 + (BUF)*32768u + (QN)*16384u + bRow + nf*2048u + c0); \
    fb[nf][1] = ds128(Bs0 + (BUF)*32768u + (QN)*16384u + bRow + nf*2048u + c1); } } while (0)

#define MMA_PH(QN) do { \
    asm volatile("s_waitcnt lgkmcnt(0)" ::: "memory"); \
    __builtin_amdgcn_sched_barrier(0); \
    __builtin_amdgcn_s_setprio(1); \
    _Pragma("unroll") for (int mf = 0; mf < 2; ++mf) \
      _Pragma("unroll") for (int nf = 0; nf < 2; ++nf) \
        _Pragma("unroll") for (int ks = 0; ks < 2; ++ks) \
          acc[QN][mf][nf] = __builtin_amdgcn_mfma_f32_16x16x32_bf16( \
              fa[mf][ks], fb[nf][ks], acc[QN][mf][nf], 0, 0, 0); \
    __builtin_amdgcn_s_setprio(0); \
} while (0)

template<int MODE>
__global__ __launch_bounds__(512, 2)
void gemm4p(const unsigned short* __restrict__ A, int lda, size_t sA,
            const unsigned short* __restrict__ Bt, int ldb, size_t sB,
            float* __restrict__ aux,
            void* __restrict__ Cout, int ldc, size_t sC,
            int N, int K, float scale)
{
    __shared__ __align__(16) unsigned short As[2][4096];     // 2 x 64x64 (16KB)
    __shared__ __align__(16) unsigned short Bs[2][16384];    // 2 x 256x64 (64KB)
    int nbn = N >> 8;
    int bid = xcd_swz((int)blockIdx.x, (int)gridDim.x);
    int bm = bid / nbn, bn = bid % nbn;
    int bz = blockIdx.y;
    int tid = threadIdx.x;
    int lane = tid & 63;
    int wid  = tid >> 6;
    int wm = (wid >> 2) & 1;
    int wn = wid & 3;
    int rlo = lane & 15;
    int shi = lane >> 4;

    unsigned As0 = (unsigned)(uintptr_t)&As[0][0];
    unsigned Bs0 = (unsigned)(uintptr_t)&Bs[0][0];
    unsigned c0 = (unsigned)(((shi     ^ rlo) & 7) * 16);
    unsigned c1 = (unsigned)((((4+shi) ^ rlo) & 7) * 16);
    unsigned aRow = (unsigned)((wm*32 + rlo) * 128);
    unsigned bRow = (unsigned)((wn*32 + rlo) * 128);

    f32x4 acc[2][2][2];
    #pragma unroll
    for (int a = 0; a < 2; a++)
        #pragma unroll
        for (int b = 0; b < 2; b++)
            #pragma unroll
            for (int c = 0; c < 2; c++)
                acc[a][b][c] = (f32x4){0.f,0.f,0.f,0.f};

    const unsigned short* Ab = A + sA*bz + (size_t)(bm*64)*lda;
    const unsigned short* Bb = Bt + sB*bz + (size_t)(bn*256)*ldb;

    // prologue: {A_E, B_E.h0, B_E.h1, A_O, B_O.h0} = 8 loads; vmcnt(3)
    stageA64(Ab, lda, &As[0][0], 0, tid, wid);
    stageB(Bb, ldb, &Bs[0][0], 0, 0,  tid, wid);
    stageB(Bb, ldb, &Bs[0][0], 1, 0,  tid, wid);
    stageA64(Ab, lda, &As[1][0], 64, tid, wid);
    stageB(Bb, ldb, &Bs[1][0], 0, 64, tid, wid);
    SB;
    asm volatile("s_waitcnt vmcnt(3)" ::: "memory");
    FENCE_BARRIER;

    short8 fa[2][2], fb[2][2];
    int nt = K >> 6;          // even, >= 4
    int nit = nt >> 1;

    for (int it = 0; it < nit; ++it) {
        int kO  = (2*it + 1) << 6;
        int kE2 = (2*it + 2 < nt) ? (2*it + 2) << 6 : 0;   // dummy k keeps ledger uniform
        int kO2 = (2*it + 3 < nt) ? (2*it + 3) << 6 : 0;

        // p1: reads A_E + B_E qn0; stage O.Bh1; pace; MFMA E qn0
        RD_A(0); RD_B(0, 0);
        stageB(Bb, ldb, &Bs[1][0], 1, kO, tid, wid);
        asm volatile("s_waitcnt lgkmcnt(4)" ::: "memory");
        FENCE_BARRIER; MMA_PH(0); FENCE_BARRIER;
        // p2: reads B_E qn1; stage E2.A + E2.Bh0; publish O; MFMA E qn1
        RD_B(0, 1);
        stageA64(Ab, lda, &As[0][0], kE2, tid, wid);
        stageB(Bb, ldb, &Bs[0][0], 0, kE2, tid, wid);
        SB;
        asm volatile("s_waitcnt vmcnt(3)" ::: "memory");
        FENCE_BARRIER; MMA_PH(1); FENCE_BARRIER;
        // p3: reads A_O + B_O qn0; stage E2.Bh1; pace; MFMA O qn0
        RD_A(1); RD_B(1, 0);
        stageB(Bb, ldb, &Bs[0][0], 1, kE2, tid, wid);
        asm volatile("s_waitcnt lgkmcnt(4)" ::: "memory");
        FENCE_BARRIER; MMA_PH(0); FENCE_BARRIER;
        // p4: reads B_O qn1; stage O2.A + O2.Bh0; publish E2; MFMA O qn1
        RD_B(1, 1);
        stageA64(Ab, lda, &As[1][0], kO2, tid, wid);
        stageB(Bb, ldb, &Bs[1][0], 0, kO2, tid, wid);
        SB;
        asm volatile("s_waitcnt vmcnt(3)" ::: "memory");
        FENCE_BARRIER; MMA_PH(1); FENCE_BARRIER;
    }

    // drain dummy-stage DMAs; barrier so LDS is quiescent before scratch reuse
    asm volatile("s_waitcnt vmcnt(0)" ::: "memory");
    FENCE_BARRIER;

    int r0 = shi << 2;
    unsigned short* Cu = (unsigned short*)Cout + sC*bz;
    float* Cf = (float*)Cout + sC*bz;

    if constexpr (MODE == 2) {
        // write u = exp(acc*scale); accumulate per-row partial sums -> aux
        float rs[2][4];
        #pragma unroll
        for (int mf = 0; mf < 2; ++mf)
            #pragma unroll
            for (int r = 0; r < 4; ++r) rs[mf][r] = 0.f;
        #pragma unroll
        for (int qn = 0; qn < 2; ++qn)
            #pragma unroll
            for (int mf = 0; mf < 2; ++mf)
                #pragma unroll
                for (int nf = 0; nf < 2; ++nf) {
                    int col = bn*256 + qn*128 + wn*32 + nf*16 + rlo;
                    #pragma unroll
                    for (int r = 0; r < 4; ++r) {
                        int row = bm*64 + wm*32 + mf*16 + r0 + r;
                        float u = __expf(acc[qn][mf][nf][r] * scale);
                        Cu[(size_t)row*ldc + col] = f2b(u);
                        rs[mf][r] += u;
                    }
                }
        #pragma unroll
        for (int m = 1; m < 16; m <<= 1)
            #pragma unroll
            for (int mf = 0; mf < 2; ++mf)
                #pragma unroll
                for (int r = 0; r < 4; ++r)
                    rs[mf][r] += __shfl_xor(rs[mf][r], m);
        float* redL = (float*)&As[0][0];   // [64][5] scratch
        if (rlo == 0) {
            #pragma unroll
            for (int mf = 0; mf < 2; ++mf)
                #pragma unroll
                for (int r = 0; r < 4; ++r)
                    redL[(wm*32 + mf*16 + (shi<<2) + r)*5 + wn] = rs[mf][r];
        }
        __syncthreads();
        if (tid < 64) {
            float s = redL[tid*5+0] + redL[tid*5+1] + redL[tid*5+2] + redL[tid*5+3];
            aux[((size_t)bz*SEQ + bm*64 + tid)*8 + bn] = s;
        }
        return;
    }

    if constexpr (MODE == 3) {
        // per-row inv from 8 psum partials (L2-hot), applied at the C-write
        float inv[2][4];
        #pragma unroll
        for (int mf = 0; mf < 2; ++mf)
            #pragma unroll
            for (int r = 0; r < 4; ++r) {
                int row = bm*64 + wm*32 + mf*16 + r0 + r;
                const float* pp = aux + ((size_t)bz*SEQ + row)*8;
                float s = pp[0]+pp[1]+pp[2]+pp[3]+pp[4]+pp[5]+pp[6]+pp[7];
                inv[mf][r] = 1.0f / s;
            }
        #pragma unroll
        for (int qn = 0; qn < 2; ++qn)
            #pragma unroll
            for (int mf = 0; mf < 2; ++mf)
                #pragma unroll
                for (int nf = 0; nf < 2; ++nf) {
                    int col = bn*256 + qn*128 + wn*32 + nf*16 + rlo;
                    #pragma unroll
                    for (int r = 0; r < 4; ++r) {
                        int row = bm*64 + wm*32 + mf*16 + r0 + r;
                        Cf[(size_t)row*ldc + col] = acc[qn][mf][nf][r] * inv[mf][r];
                    }
                }
        return;
    }

    // MODE 0: QKV with bias
    #pragma unroll
    for (int qn = 0; qn < 2; ++qn)
        #pragma unroll
        for (int mf = 0; mf < 2; ++mf)
            #pragma unroll
            for (int nf = 0; nf < 2; ++nf) {
                int col = bn*256 + qn*128 + wn*32 + nf*16 + rlo;
                float badd = aux[col];
                #pragma unroll
                for (int r = 0; r < 4; ++r) {
                    int row = bm*64 + wm*32 + mf*16 + r0 + r;
                    Cu[(size_t)row*ldc + col] = f2b(acc[qn][mf][nf][r] + badd);
                }
            }
}

extern "C" void kernel_launch(void* const* d_in, const int* in_sizes, int n_in,
                              void* d_out, int out_size, void* d_ws, size_t ws_size,
                              hipStream_t stream)
{
    (void)in_sizes; (void)n_in; (void)out_size;
    const float* x  = (const float*)d_in[0];
    const float* Wq = (const float*)d_in[1];
    const float* bq = (const float*)d_in[2];
    const float* Wk = (const float*)d_in[3];
    const float* bk = (const float*)d_in[4];
    const float* Wv = (const float*)d_in[5];
    const float* bv = (const float*)d_in[6];
    float* out = (float*)d_out;

    unsigned short* qkv = (unsigned short*)d_ws;                    // [8192][3072]
    unsigned short* vt  = qkv + (size_t)MTOT*QKVN;                  // [4][1024][2048]
    float* biasc = (float*)(vt + (size_t)NB*DIM*SEQ);               // [3072]
    char* ovl = (char*)biasc + 65536;
    unsigned short* xb    = (unsigned short*)ovl;                   // [8192][1024]
    unsigned short* wqkvt = xb + (size_t)MTOT*DIM;                  // [3072][1024]
    unsigned short* scoresB = (unsigned short*)ovl;                 // [bpp][2048][2048] bf16

    size_t base = (size_t)MTOT*QKVN*2 + (size_t)NB*DIM*SEQ*2 + 65536;
    int bpp = 1;
    if (base + 4*((size_t)SEQ*SEQ*2 + SEQ*32) <= ws_size) bpp = 4;
    else if (base + 2*((size_t)SEQ*SEQ*2 + SEQ*32) <= ws_size) bpp = 2;
    float* psum = (float*)(scoresB + (size_t)bpp*SEQ*SEQ);          // [bpp][2048][8]

    cast_kernel<<<MTOT*DIM/8/256, 256, 0, stream>>>(x, xb, MTOT*DIM/8);
    transpose_cast3<<<dim3(256, 3), 256, 0, stream>>>(Wq, Wk, Wv, wqkvt);
    bias_concat<<<QKVN/256, 256, 0, stream>>>(bq, bk, bv, biasc);

    // fused QKV projection: grid 128x12=1536 (3.0 rounds @ 2/CU)
    gemm4p<0><<<dim3((MTOT/64)*(QKVN/256)), 512, 0, stream>>>(
        xb, DIM, 0, wqkvt, DIM, 0, biasc, qkv, QKVN, 0, QKVN, DIM, 1.f);

    transpose_b16<<<dim3((SEQ/64)*(DIM/64), NB), 256, 0, stream>>>(
        qkv + 2*DIM, (size_t)SEQ*QKVN, QKVN, vt, (size_t)DIM*SEQ, SEQ, DIM/64);

    const float scl = 1.0f / 32.0f;   // 1/sqrt(1024)
    for (int p = 0; p < NB; p += bpp) {
        const unsigned short* qp = qkv + (size_t)p*SEQ*QKVN;
        // scores: u = exp((Q.K^T)/32) bf16 + deterministic row-sum partials -> psum
        gemm4p<2><<<dim3((SEQ/64)*(SEQ/256), bpp), 512, 0, stream>>>(
            qp,       QKVN, (size_t)SEQ*QKVN,
            qp + DIM, QKVN, (size_t)SEQ*QKVN,
            psum, scoresB, SEQ, (size_t)SEQ*SEQ, SEQ, DIM, scl);
        // PV: out[i,:] = inv[i] * (U.V)[i,:] — r14 loop, inv applied in epilogue
        gemm4p<3><<<dim3((SEQ/64)*(DIM/256), bpp), 512, 0, stream>>>(
            scoresB, SEQ, (size_t)SEQ*SEQ,
            vt + (size_t)p*DIM*SEQ, SEQ, (size_t)DIM*SEQ,
            psum, out + (size_t)p*SEQ*DIM, DIM, (size_t)SEQ*DIM, DIM, SEQ, 1.f);
    }
}

// Round 18
// 168.998 us; speedup vs baseline: 1.1408x; 1.0245x over previous
//
#include <hip/hip_runtime.h>
#include <stdint.h>

#define SEQ 2048
#define DIM 1024
#define NB 4
#define MTOT (NB*SEQ)
#define QKVN (3*DIM)

typedef __attribute__((ext_vector_type(8))) short short8;
typedef __attribute__((ext_vector_type(4))) float f32x4;

__device__ __forceinline__ unsigned short f2b(float f) {
    union { float f; unsigned int u; } v; v.f = f;
    return (unsigned short)((v.u + 0x7FFFu + ((v.u >> 16) & 1u)) >> 16);
}
__device__ __forceinline__ float b2f(unsigned short u) {
    union { unsigned int i; float f; } v; v.i = ((unsigned int)u) << 16; return v.f;
}

__device__ __forceinline__ void gload_lds16(const unsigned short* g, unsigned short* l) {
    __builtin_amdgcn_global_load_lds(
        (const __attribute__((address_space(1))) void*)g,
        (__attribute__((address_space(3))) void*)l, 16, 0, 0);
}

__device__ __forceinline__ short8 ds128(unsigned addr) {
    short8 r;
    asm volatile("ds_read_b128 %0, %1" : "=v"(r) : "v"(addr));
    return r;
}

#define FENCE_BARRIER do { asm volatile("" ::: "memory"); \
    __builtin_amdgcn_s_barrier(); asm volatile("" ::: "memory"); } while (0)
#define SB __builtin_amdgcn_sched_barrier(0)

__device__ __forceinline__ int xcd_swz(int bid, int nwg) {
    if (nwg & 7) return bid;
    return (bid & 7) * (nwg >> 3) + (bid >> 3);
}

// ---------------- small memory-shape kernels ----------------

__global__ __launch_bounds__(256)
void cast_kernel(const float* __restrict__ in, unsigned short* __restrict__ out, int nchunk) {
    int i = blockIdx.x * 256 + threadIdx.x;
    if (i >= nchunk) return;
    float4 a = ((const float4*)in)[i*2];
    float4 b = ((const float4*)in)[i*2+1];
    union { unsigned short u[8]; uint4 v; } r;
    r.u[0]=f2b(a.x); r.u[1]=f2b(a.y); r.u[2]=f2b(a.z); r.u[3]=f2b(a.w);
    r.u[4]=f2b(b.x); r.u[5]=f2b(b.y); r.u[6]=f2b(b.z); r.u[7]=f2b(b.w);
    ((uint4*)out)[i] = r.v;
}

__global__ __launch_bounds__(256)
void transpose_cast3(const float* __restrict__ w0, const float* __restrict__ w1,
                     const float* __restrict__ w2, unsigned short* __restrict__ out) {
    const float* in = (blockIdx.y == 0) ? w0 : (blockIdx.y == 1) ? w1 : w2;
    unsigned short* o = out + (size_t)blockIdx.y * DIM * DIM;
    __shared__ unsigned short tile[64][66];
    int tpc = DIM >> 6;
    int tr = ((int)blockIdx.x / tpc) << 6;
    int tc = ((int)blockIdx.x % tpc) << 6;
    int t = threadIdx.x;
    #pragma unroll
    for (int i = 0; i < 16; i++) {
        int idx = t + i*256;
        int r = idx >> 6, c = idx & 63;
        tile[r][c] = f2b(in[(size_t)(tr + r)*DIM + tc + c]);
    }
    __syncthreads();
    #pragma unroll
    for (int i = 0; i < 16; i++) {
        int idx = t + i*256;
        int r = idx >> 6, c = idx & 63;
        o[(size_t)(tc + r)*DIM + tr + c] = tile[c][r];
    }
}

__global__ __launch_bounds__(256)
void bias_concat(const float* __restrict__ bq, const float* __restrict__ bk,
                 const float* __restrict__ bv, float* __restrict__ o) {
    int i = blockIdx.x*256 + threadIdx.x;
    float v = (i < DIM) ? bq[i] : ((i < 2*DIM) ? bk[i-DIM] : bv[i-2*DIM]);
    o[i] = v;
}

// -------- 64x256 4-phase pipelined GEMM, 2 blocks/CU (r14 ledger, ALL modes) --------
// Main loop identical for every MODE (global_load_lds staging everywhere).
// MODE 0: QKV — T-blocks (bn<nT): bf16(acc+aux[col]) -> C; V-blocks (bn>=nT):
//         bf16(acc+aux[col]) written TRANSPOSED to vtout (ushort4 per lane).
// MODE 2: bf16(exp(acc*scale)) + deterministic row-sum partials->aux (scores)
// MODE 3: f32(acc * inv[row]), inv from aux's 8 partials per row     (PV)
// vmcnt ledger: prologue 8 -> vmcnt(3); p1 +2; p2 +3, vmcnt(3) publish O;
// p3 +2; p4 +3, vmcnt(3) publish E2. Never 0 in loop.

__device__ __forceinline__ void stageA64(const unsigned short* __restrict__ Xb, int ldx,
                                         unsigned short* dstBase, int k0,
                                         int tid, int wid) {
    int srow = tid >> 3;
    int scol = ((tid & 7) ^ (srow & 7)) << 3;
    gload_lds16(Xb + (size_t)srow*ldx + k0 + scol, dstBase + wid*512);
}

__device__ __forceinline__ void stageB(const unsigned short* __restrict__ Xb, int ldx,
                                       unsigned short* dstBase, int h, int k0,
                                       int tid, int wid) {
    int srow = tid >> 3;
    int scol = ((tid & 7) ^ (srow & 7)) << 3;
    const unsigned short* g = Xb + (size_t)(h*128 + srow)*ldx + k0 + scol;
    unsigned short* d = dstBase + h*8192 + wid*512;
    gload_lds16(g, d);
    gload_lds16(g + (size_t)64*ldx, d + 4096);
}

#define RD_A(BUF) do { _Pragma("unroll") for (int mf = 0; mf < 2; ++mf) { \
    fa[mf][0] = ds128(As0 + (BUF)*8192u + aRow + mf*2048u + c0); \
    fa[mf][1] = ds128(As0 + (BUF)*8192u + aRow + mf*2048u + c1); } } while (0)

#define RD_B(BUF, QN) do { _Pragma("unroll") for (int nf = 0; nf < 2; ++nf) { \
    fb[nf][0] = ds128(Bs0 + (BUF)*32768u + (QN)*16384u + bRow + nf*2048u + c0); \
    fb[nf][1] = ds128(Bs0 + (BUF)*32768u + (QN)*16384u + bRow + nf*2048u + c1); } } while (0)

#define MMA_PH(QN) do { \
    asm volatile("s_waitcnt lgkmcnt(0)" ::: "memory"); \
    __builtin_amdgcn_sched_barrier(0); \
    __builtin_amdgcn_s_setprio(1); \
    _Pragma("unroll") for (int mf = 0; mf < 2; ++mf) \
      _Pragma("unroll") for (int nf = 0; nf < 2; ++nf) \
        _Pragma("unroll") for (int ks = 0; ks < 2; ++ks) \
          acc[QN][mf][nf] = __builtin_amdgcn_mfma_f32_16x16x32_bf16( \
              fa[mf][ks], fb[nf][ks], acc[QN][mf][nf], 0, 0, 0); \
    __builtin_amdgcn_s_setprio(0); \
} while (0)

template<int MODE>
__global__ __launch_bounds__(512, 2)
void gemm4p(const unsigned short* __restrict__ A, int lda, size_t sA,
            const unsigned short* __restrict__ Bt, int ldb, size_t sB,
            float* __restrict__ aux,
            void* __restrict__ Cout, int ldc, size_t sC,
            int N, int K, float scale,
            unsigned short* __restrict__ vtout, int nT)
{
    __shared__ __align__(16) unsigned short As[2][4096];     // 2 x 64x64 (16KB)
    __shared__ __align__(16) unsigned short Bs[2][16384];    // 2 x 256x64 (64KB)
    int nbn = N >> 8;
    int bid = xcd_swz((int)blockIdx.x, (int)gridDim.x);
    int bm = bid / nbn, bn = bid % nbn;
    int bz = blockIdx.y;
    int tid = threadIdx.x;
    int lane = tid & 63;
    int wid  = tid >> 6;
    int wm = (wid >> 2) & 1;
    int wn = wid & 3;
    int rlo = lane & 15;
    int shi = lane >> 4;

    unsigned As0 = (unsigned)(uintptr_t)&As[0][0];
    unsigned Bs0 = (unsigned)(uintptr_t)&Bs[0][0];
    unsigned c0 = (unsigned)(((shi     ^ rlo) & 7) * 16);
    unsigned c1 = (unsigned)((((4+shi) ^ rlo) & 7) * 16);
    unsigned aRow = (unsigned)((wm*32 + rlo) * 128);
    unsigned bRow = (unsigned)((wn*32 + rlo) * 128);

    f32x4 acc[2][2][2];
    #pragma unroll
    for (int a = 0; a < 2; a++)
        #pragma unroll
        for (int b = 0; b < 2; b++)
            #pragma unroll
            for (int c = 0; c < 2; c++)
                acc[a][b][c] = (f32x4){0.f,0.f,0.f,0.f};

    const unsigned short* Ab = A + sA*bz + (size_t)(bm*64)*lda;
    const unsigned short* Bb = Bt + sB*bz + (size_t)(bn*256)*ldb;

    // prologue: {A_E, B_E.h0, B_E.h1, A_O, B_O.h0} = 8 loads; vmcnt(3)
    stageA64(Ab, lda, &As[0][0], 0, tid, wid);
    stageB(Bb, ldb, &Bs[0][0], 0, 0,  tid, wid);
    stageB(Bb, ldb, &Bs[0][0], 1, 0,  tid, wid);
    stageA64(Ab, lda, &As[1][0], 64, tid, wid);
    stageB(Bb, ldb, &Bs[1][0], 0, 64, tid, wid);
    SB;
    asm volatile("s_waitcnt vmcnt(3)" ::: "memory");
    FENCE_BARRIER;

    short8 fa[2][2], fb[2][2];
    int nt = K >> 6;          // even, >= 4
    int nit = nt >> 1;

    for (int it = 0; it < nit; ++it) {
        int kO  = (2*it + 1) << 6;
        int kE2 = (2*it + 2 < nt) ? (2*it + 2) << 6 : 0;   // dummy k keeps ledger uniform
        int kO2 = (2*it + 3 < nt) ? (2*it + 3) << 6 : 0;

        // p1: reads A_E + B_E qn0; stage O.Bh1; pace; MFMA E qn0
        RD_A(0); RD_B(0, 0);
        stageB(Bb, ldb, &Bs[1][0], 1, kO, tid, wid);
        asm volatile("s_waitcnt lgkmcnt(4)" ::: "memory");
        FENCE_BARRIER; MMA_PH(0); FENCE_BARRIER;
        // p2: reads B_E qn1; stage E2.A + E2.Bh0; publish O; MFMA E qn1
        RD_B(0, 1);
        stageA64(Ab, lda, &As[0][0], kE2, tid, wid);
        stageB(Bb, ldb, &Bs[0][0], 0, kE2, tid, wid);
        SB;
        asm volatile("s_waitcnt vmcnt(3)" ::: "memory");
        FENCE_BARRIER; MMA_PH(1); FENCE_BARRIER;
        // p3: reads A_O + B_O qn0; stage E2.Bh1; pace; MFMA O qn0
        RD_A(1); RD_B(1, 0);
        stageB(Bb, ldb, &Bs[0][0], 1, kE2, tid, wid);
        asm volatile("s_waitcnt lgkmcnt(4)" ::: "memory");
        FENCE_BARRIER; MMA_PH(0); FENCE_BARRIER;
        // p4: reads B_O qn1; stage O2.A + O2.Bh0; publish E2; MFMA O qn1
        RD_B(1, 1);
        stageA64(Ab, lda, &As[1][0], kO2, tid, wid);
        stageB(Bb, ldb, &Bs[1][0], 0, kO2, tid, wid);
        SB;
        asm volatile("s_waitcnt vmcnt(3)" ::: "memory");
        FENCE_BARRIER; MMA_PH(1); FENCE_BARRIER;
    }

    // drain dummy-stage DMAs; barrier so LDS is quiescent before scratch reuse
    asm volatile("s_waitcnt vmcnt(0)" ::: "memory");
    FENCE_BARRIER;

    int r0 = shi << 2;
    unsigned short* Cu = (unsigned short*)Cout + sC*bz;
    float* Cf = (float*)Cout + sC*bz;

    if constexpr (MODE == 2) {
        // write u = exp(acc*scale); accumulate per-row partial sums -> aux
        float rs[2][4];
        #pragma unroll
        for (int mf = 0; mf < 2; ++mf)
            #pragma unroll
            for (int r = 0; r < 4; ++r) rs[mf][r] = 0.f;
        #pragma unroll
        for (int qn = 0; qn < 2; ++qn)
            #pragma unroll
            for (int mf = 0; mf < 2; ++mf)
                #pragma unroll
                for (int nf = 0; nf < 2; ++nf) {
                    int col = bn*256 + qn*128 + wn*32 + nf*16 + rlo;
                    #pragma unroll
                    for (int r = 0; r < 4; ++r) {
                        int row = bm*64 + wm*32 + mf*16 + r0 + r;
                        float u = __expf(acc[qn][mf][nf][r] * scale);
                        Cu[(size_t)row*ldc + col] = f2b(u);
                        rs[mf][r] += u;
                    }
                }
        #pragma unroll
        for (int m = 1; m < 16; m <<= 1)
            #pragma unroll
            for (int mf = 0; mf < 2; ++mf)
                #pragma unroll
                for (int r = 0; r < 4; ++r)
                    rs[mf][r] += __shfl_xor(rs[mf][r], m);
        float* redL = (float*)&As[0][0];   // [64][5] scratch
        if (rlo == 0) {
            #pragma unroll
            for (int mf = 0; mf < 2; ++mf)
                #pragma unroll
                for (int r = 0; r < 4; ++r)
                    redL[(wm*32 + mf*16 + (shi<<2) + r)*5 + wn] = rs[mf][r];
        }
        __syncthreads();
        if (tid < 64) {
            float s = redL[tid*5+0] + redL[tid*5+1] + redL[tid*5+2] + redL[tid*5+3];
            aux[((size_t)bz*SEQ + bm*64 + tid)*8 + bn] = s;
        }
        return;
    }

    if constexpr (MODE == 3) {
        // per-row inv from 8 psum partials (L2-hot), applied at the C-write
        float inv[2][4];
        #pragma unroll
        for (int mf = 0; mf < 2; ++mf)
            #pragma unroll
            for (int r = 0; r < 4; ++r) {
                int row = bm*64 + wm*32 + mf*16 + r0 + r;
                const float* pp = aux + ((size_t)bz*SEQ + row)*8;
                float s = pp[0]+pp[1]+pp[2]+pp[3]+pp[4]+pp[5]+pp[6]+pp[7];
                inv[mf][r] = 1.0f / s;
            }
        #pragma unroll
        for (int qn = 0; qn < 2; ++qn)
            #pragma unroll
            for (int mf = 0; mf < 2; ++mf)
                #pragma unroll
                for (int nf = 0; nf < 2; ++nf) {
                    int col = bn*256 + qn*128 + wn*32 + nf*16 + rlo;
                    #pragma unroll
                    for (int r = 0; r < 4; ++r) {
                        int row = bm*64 + wm*32 + mf*16 + r0 + r;
                        Cf[(size_t)row*ldc + col] = acc[qn][mf][nf][r] * inv[mf][r];
                    }
                }
        return;
    }

    // MODE 0: QKV with bias. T-blocks -> C rows; V-blocks -> transposed vt.
    if (bn < nT) {
        #pragma unroll
        for (int qn = 0; qn < 2; ++qn)
            #pragma unroll
            for (int mf = 0; mf < 2; ++mf)
                #pragma unroll
                for (int nf = 0; nf < 2; ++nf) {
                    int col = bn*256 + qn*128 + wn*32 + nf*16 + rlo;
                    float badd = aux[col];
                    #pragma unroll
                    for (int r = 0; r < 4; ++r) {
                        int row = bm*64 + wm*32 + mf*16 + r0 + r;
                        Cu[(size_t)row*ldc + col] = f2b(acc[qn][mf][nf][r] + badd);
                    }
                }
    } else {
        // V-part: vt[b][colv][seq] ; 4 consecutive rows = 1 ushort4 store
        #pragma unroll
        for (int qn = 0; qn < 2; ++qn)
            #pragma unroll
            for (int mf = 0; mf < 2; ++mf)
                #pragma unroll
                for (int nf = 0; nf < 2; ++nf) {
                    int col  = bn*256 + qn*128 + wn*32 + nf*16 + rlo;
                    int colv = col - nT*256;
                    float badd = aux[col];
                    int row = bm*64 + wm*32 + mf*16 + r0;     // 4 consecutive
                    int b  = row >> 11, sr = row & 2047;
                    ushort4 w;
                    w.x = f2b(acc[qn][mf][nf][0] + badd);
                    w.y = f2b(acc[qn][mf][nf][1] + badd);
                    w.z = f2b(acc[qn][mf][nf][2] + badd);
                    w.w = f2b(acc[qn][mf][nf][3] + badd);
                    *(ushort4*)(vtout + (size_t)b*DIM*SEQ + (size_t)colv*SEQ + sr) = w;
                }
    }
}

extern "C" void kernel_launch(void* const* d_in, const int* in_sizes, int n_in,
                              void* d_out, int out_size, void* d_ws, size_t ws_size,
                              hipStream_t stream)
{
    (void)in_sizes; (void)n_in; (void)out_size;
    const float* x  = (const float*)d_in[0];
    const float* Wq = (const float*)d_in[1];
    const float* bq = (const float*)d_in[2];
    const float* Wk = (const float*)d_in[3];
    const float* bk = (const float*)d_in[4];
    const float* Wv = (const float*)d_in[5];
    const float* bv = (const float*)d_in[6];
    float* out = (float*)d_out;

    unsigned short* qkv = (unsigned short*)d_ws;                    // [8192][3072] (V cols unused)
    unsigned short* vt  = qkv + (size_t)MTOT*QKVN;                  // [4][1024][2048]
    float* biasc = (float*)(vt + (size_t)NB*DIM*SEQ);               // [3072]
    char* ovl = (char*)biasc + 65536;
    unsigned short* xb    = (unsigned short*)ovl;                   // [8192][1024]
    unsigned short* wqkvt = xb + (size_t)MTOT*DIM;                  // [3072][1024]
    unsigned short* scoresB = (unsigned short*)ovl;                 // [bpp][2048][2048] bf16

    size_t base = (size_t)MTOT*QKVN*2 + (size_t)NB*DIM*SEQ*2 + 65536;
    int bpp = 1;
    if (base + 4*((size_t)SEQ*SEQ*2 + SEQ*32) <= ws_size) bpp = 4;
    else if (base + 2*((size_t)SEQ*SEQ*2 + SEQ*32) <= ws_size) bpp = 2;
    float* psum = (float*)(scoresB + (size_t)bpp*SEQ*SEQ);          // [bpp][2048][8]

    cast_kernel<<<MTOT*DIM/8/256, 256, 0, stream>>>(x, xb, MTOT*DIM/8);
    transpose_cast3<<<dim3(256, 3), 256, 0, stream>>>(Wq, Wk, Wv, wqkvt);
    bias_concat<<<QKVN/256, 256, 0, stream>>>(bq, bk, bv, biasc);

    // fused QKV projection: grid 128x12=1536 (3.0 rounds @ 2/CU)
    // T-blocks (bn<8) -> qkv rows; V-blocks (bn>=8) -> vt transposed (no transpose kernel)
    gemm4p<0><<<dim3((MTOT/64)*(QKVN/256)), 512, 0, stream>>>(
        xb, DIM, 0, wqkvt, DIM, 0, biasc, qkv, QKVN, 0, QKVN, DIM, 1.f, vt, 8);

    const float scl = 1.0f / 32.0f;   // 1/sqrt(1024)
    for (int p = 0; p < NB; p += bpp) {
        const unsigned short* qp = qkv + (size_t)p*SEQ*QKVN;
        // scores: u = exp((Q.K^T)/32) bf16 + deterministic row-sum partials -> psum
        gemm4p<2><<<dim3((SEQ/64)*(SEQ/256), bpp), 512, 0, stream>>>(
            qp,       QKVN, (size_t)SEQ*QKVN,
            qp + DIM, QKVN, (size_t)SEQ*QKVN,
            psum, scoresB, SEQ, (size_t)SEQ*SEQ, SEQ, DIM, scl, nullptr, 0);
        // PV: out[i,:] = inv[i] * (U.V)[i,:] — r14 loop, inv applied in epilogue
        gemm4p<3><<<dim3((SEQ/64)*(DIM/256), bpp), 512, 0, stream>>>(
            scoresB, SEQ, (size_t)SEQ*SEQ,
            vt + (size_t)p*DIM*SEQ, SEQ, (size_t)DIM*SEQ,
            psum, out + (size_t)p*SEQ*DIM, DIM, (size_t)SEQ*DIM, DIM, SEQ, 1.f, nullptr, 0);
    }
}

// Round 19
// 165.364 us; speedup vs baseline: 1.1658x; 1.0220x over previous
//
#include <hip/hip_runtime.h>
#include <stdint.h>

#define SEQ 2048
#define DIM 1024
#define NB 4
#define MTOT (NB*SEQ)
#define QKVN (3*DIM)

typedef __attribute__((ext_vector_type(8))) short short8;
typedef __attribute__((ext_vector_type(4))) float f32x4;

__device__ __forceinline__ unsigned short f2b(float f) {
    union { float f; unsigned int u; } v; v.f = f;
    return (unsigned short)((v.u + 0x7FFFu + ((v.u >> 16) & 1u)) >> 16);
}
__device__ __forceinline__ float b2f(unsigned short u) {
    union { unsigned int i; float f; } v; v.i = ((unsigned int)u) << 16; return v.f;
}

__device__ __forceinline__ void gload_lds16(const unsigned short* g, unsigned short* l) {
    __builtin_amdgcn_global_load_lds(
        (const __attribute__((address_space(1))) void*)g,
        (__attribute__((address_space(3))) void*)l, 16, 0, 0);
}

__device__ __forceinline__ short8 ds128(unsigned addr) {
    short8 r;
    asm volatile("ds_read_b128 %0, %1" : "=v"(r) : "v"(addr));
    return r;
}

#define FENCE_BARRIER do { asm volatile("" ::: "memory"); \
    __builtin_amdgcn_s_barrier(); asm volatile("" ::: "memory"); } while (0)
#define SB __builtin_amdgcn_sched_barrier(0)

__device__ __forceinline__ int xcd_swz(int bid, int nwg) {
    if (nwg & 7) return bid;
    return (bid & 7) * (nwg >> 3) + (bid >> 3);
}

// ---------------- fused prep: cast(x) + transpose-cast(Wq,Wk,Wv) + bias ----------------
__global__ __launch_bounds__(256)
void prep(const float* __restrict__ x,
          const float* __restrict__ Wq, const float* __restrict__ Wk,
          const float* __restrict__ Wv,
          const float* __restrict__ bq, const float* __restrict__ bk,
          const float* __restrict__ bv,
          unsigned short* __restrict__ xb, unsigned short* __restrict__ wqkvt,
          float* __restrict__ biasc)
{
    __shared__ unsigned short tile[64][66];
    int b = blockIdx.x;
    int t = threadIdx.x;
    if (b < 4096) {                       // cast x -> xb (8 bf16/thread)
        int i = b*256 + t;
        float4 a = ((const float4*)x)[(size_t)i*2];
        float4 c = ((const float4*)x)[(size_t)i*2+1];
        union { unsigned short u[8]; uint4 v; } r;
        r.u[0]=f2b(a.x); r.u[1]=f2b(a.y); r.u[2]=f2b(a.z); r.u[3]=f2b(a.w);
        r.u[4]=f2b(c.x); r.u[5]=f2b(c.y); r.u[6]=f2b(c.z); r.u[7]=f2b(c.w);
        ((uint4*)xb)[i] = r.v;
        return;
    }
    if (b < 4864) {                       // transpose-cast one 64x64 tile of W
        int bb = b - 4096;
        int y = bb >> 8;                  // 0..2 selects Wq/Wk/Wv
        int bx = bb & 255;
        const float* in = (y == 0) ? Wq : (y == 1) ? Wk : Wv;
        unsigned short* o = wqkvt + (size_t)y * DIM * DIM;
        int tpc = DIM >> 6;
        int tr = (bx / tpc) << 6;
        int tc = (bx % tpc) << 6;
        #pragma unroll
        for (int i = 0; i < 16; i++) {
            int idx = t + i*256;
            int r = idx >> 6, c = idx & 63;
            tile[r][c] = f2b(in[(size_t)(tr + r)*DIM + tc + c]);
        }
        __syncthreads();
        #pragma unroll
        for (int i = 0; i < 16; i++) {
            int idx = t + i*256;
            int r = idx >> 6, c = idx & 63;
            o[(size_t)(tc + r)*DIM + tr + c] = tile[c][r];
        }
        return;
    }
    int i = (b - 4864)*256 + t;           // bias concat (3072 elems, 12 blocks)
    float v = (i < DIM) ? bq[i] : ((i < 2*DIM) ? bk[i-DIM] : bv[i-2*DIM]);
    biasc[i] = v;
}

// -------- 64x256 4-phase pipelined GEMM, 2 blocks/CU (r14 ledger, ALL modes) --------
// MODE 0: QKV — T-blocks (bn<nT): bf16(acc+aux[col]) -> C; V-blocks (bn>=nT):
//         bf16(acc+aux[col]) -> LDS-coalesced transposed write to vtout.
// MODE 2: bf16(exp(acc*scale)) + deterministic row-sum partials->aux (scores)
// MODE 3: f32(acc * inv[row]), inv from aux's 8 partials per row     (PV)
// vmcnt ledger: prologue 8 -> vmcnt(3); p1 +2; p2 +3, vmcnt(3) publish O;
// p3 +2; p4 +3, vmcnt(3) publish E2. Never 0 in loop.

__device__ __forceinline__ void stageA64(const unsigned short* __restrict__ Xb, int ldx,
                                         unsigned short* dstBase, int k0,
                                         int tid, int wid) {
    int srow = tid >> 3;
    int scol = ((tid & 7) ^ (srow & 7)) << 3;
    gload_lds16(Xb + (size_t)srow*ldx + k0 + scol, dstBase + wid*512);
}

__device__ __forceinline__ void stageB(const unsigned short* __restrict__ Xb, int ldx,
                                       unsigned short* dstBase, int h, int k0,
                                       int tid, int wid) {
    int srow = tid >> 3;
    int scol = ((tid & 7) ^ (srow & 7)) << 3;
    const unsigned short* g = Xb + (size_t)(h*128 + srow)*ldx + k0 + scol;
    unsigned short* d = dstBase + h*8192 + wid*512;
    gload_lds16(g, d);
    gload_lds16(g + (size_t)64*ldx, d + 4096);
}

#define RD_A(BUF) do { _Pragma("unroll") for (int mf = 0; mf < 2; ++mf) { \
    fa[mf][0] = ds128(As0 + (BUF)*8192u + aRow + mf*2048u + c0); \
    fa[mf][1] = ds128(As0 + (BUF)*8192u + aRow + mf*2048u + c1); } } while (0)

#define RD_B(BUF, QN) do { _Pragma("unroll") for (int nf = 0; nf < 2; ++nf) { \
    fb[nf][0] = ds128(Bs0 + (BUF)*32768u + (QN)*16384u + bRow + nf*2048u + c0); \
    fb[nf][1] = ds128(Bs0 + (BUF)*32768u + (QN)*16384u + bRow + nf*2048u + c1); } } while (0)

#define MMA_PH(QN) do { \
    asm volatile("s_waitcnt lgkmcnt(0)" ::: "memory"); \
    __builtin_amdgcn_sched_barrier(0); \
    __builtin_amdgcn_s_setprio(1); \
    _Pragma("unroll") for (int mf = 0; mf < 2; ++mf) \
      _Pragma("unroll") for (int nf = 0; nf < 2; ++nf) \
        _Pragma("unroll") for (int ks = 0; ks < 2; ++ks) \
          acc[QN][mf][nf] = __builtin_amdgcn_mfma_f32_16x16x32_bf16( \
              fa[mf][ks], fb[nf][ks], acc[QN][mf][nf], 0, 0, 0); \
    __builtin_amdgcn_s_setprio(0); \
} while (0)

template<int MODE>
__global__ __launch_bounds__(512, 2)
void gemm4p(const unsigned short* __restrict__ A, int lda, size_t sA,
            const unsigned short* __restrict__ Bt, int ldb, size_t sB,
            float* __restrict__ aux,
            void* __restrict__ Cout, int ldc, size_t sC,
            int N, int K, float scale,
            unsigned short* __restrict__ vtout, int nT)
{
    __shared__ __align__(16) unsigned short As[2][4096];     // 2 x 64x64 (16KB)
    __shared__ __align__(16) unsigned short Bs[2][16384];    // 2 x 256x64 (64KB)
    int nbn = N >> 8;
    int bid = xcd_swz((int)blockIdx.x, (int)gridDim.x);
    int bm = bid / nbn, bn = bid % nbn;
    int bz = blockIdx.y;
    int tid = threadIdx.x;
    int lane = tid & 63;
    int wid  = tid >> 6;
    int wm = (wid >> 2) & 1;
    int wn = wid & 3;
    int rlo = lane & 15;
    int shi = lane >> 4;

    unsigned As0 = (unsigned)(uintptr_t)&As[0][0];
    unsigned Bs0 = (unsigned)(uintptr_t)&Bs[0][0];
    unsigned c0 = (unsigned)(((shi     ^ rlo) & 7) * 16);
    unsigned c1 = (unsigned)((((4+shi) ^ rlo) & 7) * 16);
    unsigned aRow = (unsigned)((wm*32 + rlo) * 128);
    unsigned bRow = (unsigned)((wn*32 + rlo) * 128);

    f32x4 acc[2][2][2];
    #pragma unroll
    for (int a = 0; a < 2; a++)
        #pragma unroll
        for (int b = 0; b < 2; b++)
            #pragma unroll
            for (int c = 0; c < 2; c++)
                acc[a][b][c] = (f32x4){0.f,0.f,0.f,0.f};

    const unsigned short* Ab = A + sA*bz + (size_t)(bm*64)*lda;
    const unsigned short* Bb = Bt + sB*bz + (size_t)(bn*256)*ldb;

    // prologue: {A_E, B_E.h0, B_E.h1, A_O, B_O.h0} = 8 loads; vmcnt(3)
    stageA64(Ab, lda, &As[0][0], 0, tid, wid);
    stageB(Bb, ldb, &Bs[0][0], 0, 0,  tid, wid);
    stageB(Bb, ldb, &Bs[0][0], 1, 0,  tid, wid);
    stageA64(Ab, lda, &As[1][0], 64, tid, wid);
    stageB(Bb, ldb, &Bs[1][0], 0, 64, tid, wid);
    SB;
    asm volatile("s_waitcnt vmcnt(3)" ::: "memory");
    FENCE_BARRIER;

    short8 fa[2][2], fb[2][2];
    int nt = K >> 6;          // even, >= 4
    int nit = nt >> 1;

    for (int it = 0; it < nit; ++it) {
        int kO  = (2*it + 1) << 6;
        int kE2 = (2*it + 2 < nt) ? (2*it + 2) << 6 : 0;   // dummy k keeps ledger uniform
        int kO2 = (2*it + 3 < nt) ? (2*it + 3) << 6 : 0;

        // p1: reads A_E + B_E qn0; stage O.Bh1; pace; MFMA E qn0
        RD_A(0); RD_B(0, 0);
        stageB(Bb, ldb, &Bs[1][0], 1, kO, tid, wid);
        asm volatile("s_waitcnt lgkmcnt(4)" ::: "memory");
        FENCE_BARRIER; MMA_PH(0); FENCE_BARRIER;
        // p2: reads B_E qn1; stage E2.A + E2.Bh0; publish O; MFMA E qn1
        RD_B(0, 1);
        stageA64(Ab, lda, &As[0][0], kE2, tid, wid);
        stageB(Bb, ldb, &Bs[0][0], 0, kE2, tid, wid);
        SB;
        asm volatile("s_waitcnt vmcnt(3)" ::: "memory");
        FENCE_BARRIER; MMA_PH(1); FENCE_BARRIER;
        // p3: reads A_O + B_O qn0; stage E2.Bh1; pace; MFMA O qn0
        RD_A(1); RD_B(1, 0);
        stageB(Bb, ldb, &Bs[0][0], 1, kE2, tid, wid);
        asm volatile("s_waitcnt lgkmcnt(4)" ::: "memory");
        FENCE_BARRIER; MMA_PH(0); FENCE_BARRIER;
        // p4: reads B_O qn1; stage O2.A + O2.Bh0; publish E2; MFMA O qn1
        RD_B(1, 1);
        stageA64(Ab, lda, &As[1][0], kO2, tid, wid);
        stageB(Bb, ldb, &Bs[1][0], 0, kO2, tid, wid);
        SB;
        asm volatile("s_waitcnt vmcnt(3)" ::: "memory");
        FENCE_BARRIER; MMA_PH(1); FENCE_BARRIER;
    }

    // drain dummy-stage DMAs; barrier so LDS is quiescent before scratch reuse
    asm volatile("s_waitcnt vmcnt(0)" ::: "memory");
    FENCE_BARRIER;

    int r0 = shi << 2;
    unsigned short* Cu = (unsigned short*)Cout + sC*bz;
    float* Cf = (float*)Cout + sC*bz;

    if constexpr (MODE == 2) {
        // write u = exp(acc*scale); accumulate per-row partial sums -> aux
        float rs[2][4];
        #pragma unroll
        for (int mf = 0; mf < 2; ++mf)
            #pragma unroll
            for (int r = 0; r < 4; ++r) rs[mf][r] = 0.f;
        #pragma unroll
        for (int qn = 0; qn < 2; ++qn)
            #pragma unroll
            for (int mf = 0; mf < 2; ++mf)
                #pragma unroll
                for (int nf = 0; nf < 2; ++nf) {
                    int col = bn*256 + qn*128 + wn*32 + nf*16 + rlo;
                    #pragma unroll
                    for (int r = 0; r < 4; ++r) {
                        int row = bm*64 + wm*32 + mf*16 + r0 + r;
                        float u = __expf(acc[qn][mf][nf][r] * scale);
                        Cu[(size_t)row*ldc + col] = f2b(u);
                        rs[mf][r] += u;
                    }
                }
        #pragma unroll
        for (int m = 1; m < 16; m <<= 1)
            #pragma unroll
            for (int mf = 0; mf < 2; ++mf)
                #pragma unroll
                for (int r = 0; r < 4; ++r)
                    rs[mf][r] += __shfl_xor(rs[mf][r], m);
        float* redL = (float*)&As[0][0];   // [64][5] scratch
        if (rlo == 0) {
            #pragma unroll
            for (int mf = 0; mf < 2; ++mf)
                #pragma unroll
                for (int r = 0; r < 4; ++r)
                    redL[(wm*32 + mf*16 + (shi<<2) + r)*5 + wn] = rs[mf][r];
        }
        __syncthreads();
        if (tid < 64) {
            float s = redL[tid*5+0] + redL[tid*5+1] + redL[tid*5+2] + redL[tid*5+3];
            aux[((size_t)bz*SEQ + bm*64 + tid)*8 + bn] = s;
        }
        return;
    }

    if constexpr (MODE == 3) {
        // per-row inv from 8 psum partials (L2-hot), applied at the C-write
        float inv[2][4];
        #pragma unroll
        for (int mf = 0; mf < 2; ++mf)
            #pragma unroll
            for (int r = 0; r < 4; ++r) {
                int row = bm*64 + wm*32 + mf*16 + r0 + r;
                const float* pp = aux + ((size_t)bz*SEQ + row)*8;
                float s = pp[0]+pp[1]+pp[2]+pp[3]+pp[4]+pp[5]+pp[6]+pp[7];
                inv[mf][r] = 1.0f / s;
            }
        #pragma unroll
        for (int qn = 0; qn < 2; ++qn)
            #pragma unroll
            for (int mf = 0; mf < 2; ++mf)
                #pragma unroll
                for (int nf = 0; nf < 2; ++nf) {
                    int col = bn*256 + qn*128 + wn*32 + nf*16 + rlo;
                    #pragma unroll
                    for (int r = 0; r < 4; ++r) {
                        int row = bm*64 + wm*32 + mf*16 + r0 + r;
                        Cf[(size_t)row*ldc + col] = acc[qn][mf][nf][r] * inv[mf][r];
                    }
                }
        return;
    }

    // MODE 0: QKV with bias. T-blocks -> C rows; V-blocks -> vt via LDS transpose.
    if (bn < nT) {
        #pragma unroll
        for (int qn = 0; qn < 2; ++qn)
            #pragma unroll
            for (int mf = 0; mf < 2; ++mf)
                #pragma unroll
                for (int nf = 0; nf < 2; ++nf) {
                    int col = bn*256 + qn*128 + wn*32 + nf*16 + rlo;
                    float badd = aux[col];
                    #pragma unroll
                    for (int r = 0; r < 4; ++r) {
                        int row = bm*64 + wm*32 + mf*16 + r0 + r;
                        Cu[(size_t)row*ldc + col] = f2b(acc[qn][mf][nf][r] + badd);
                    }
                }
    } else {
        // V-part: stage [256 colv][64 sl] tile in Bs (XOR bank-swizzled),
        // then fully-coalesced 16B stores to vt[b][colv][seq].
        unsigned short* vtile = &Bs[0][0];    // 32KB, DMA-drained
        #pragma unroll
        for (int qn = 0; qn < 2; ++qn)
            #pragma unroll
            for (int mf = 0; mf < 2; ++mf)
                #pragma unroll
                for (int nf = 0; nf < 2; ++nf) {
                    int col  = bn*256 + qn*128 + wn*32 + nf*16 + rlo;
                    int colv = qn*128 + wn*32 + nf*16 + rlo;
                    float badd = aux[col];
                    int sl0 = wm*32 + mf*16 + r0;           // 4 consecutive sl
                    ushort4 w;
                    w.x = f2b(acc[qn][mf][nf][0] + badd);
                    w.y = f2b(acc[qn][mf][nf][1] + badd);
                    w.z = f2b(acc[qn][mf][nf][2] + badd);
                    w.w = f2b(acc[qn][mf][nf][3] + badd);
                    unsigned off = (unsigned)colv*128u + (((unsigned)sl0*2u) ^ (((unsigned)colv & 7u) << 4));
                    *(ushort4*)((char*)vtile + off) = w;
                }
        __syncthreads();
        int b  = (bm*64) >> 11;
        int sr = (bm*64) & 2047;
        unsigned short* vtb = vtout + (size_t)b*DIM*SEQ + (size_t)((bn - nT)*256)*SEQ + sr;
        #pragma unroll
        for (int i = 0; i < 4; ++i) {
            int cl = i*64 + (tid >> 3);                     // 0..255
            int so = (tid & 7) * 8;                         // 0..56
            unsigned off = (unsigned)cl*128u + (((unsigned)so*2u) ^ (((unsigned)cl & 7u) << 4));
            short8 vv = *(short8*)((char*)vtile + off);
            *(short8*)(vtb + (size_t)cl*SEQ + so) = vv;
        }
    }
}

extern "C" void kernel_launch(void* const* d_in, const int* in_sizes, int n_in,
                              void* d_out, int out_size, void* d_ws, size_t ws_size,
                              hipStream_t stream)
{
    (void)in_sizes; (void)n_in; (void)out_size;
    const float* x  = (const float*)d_in[0];
    const float* Wq = (const float*)d_in[1];
    const float* bq = (const float*)d_in[2];
    const float* Wk = (const float*)d_in[3];
    const float* bk = (const float*)d_in[4];
    const float* Wv = (const float*)d_in[5];
    const float* bv = (const float*)d_in[6];
    float* out = (float*)d_out;

    unsigned short* qkv = (unsigned short*)d_ws;                    // [8192][3072] (V cols unused)
    unsigned short* vt  = qkv + (size_t)MTOT*QKVN;                  // [4][1024][2048]
    float* biasc = (float*)(vt + (size_t)NB*DIM*SEQ);               // [3072]
    char* ovl = (char*)biasc + 65536;
    unsigned short* xb    = (unsigned short*)ovl;                   // [8192][1024]
    unsigned short* wqkvt = xb + (size_t)MTOT*DIM;                  // [3072][1024]
    unsigned short* scoresB = (unsigned short*)ovl;                 // [bpp][2048][2048] bf16

    size_t base = (size_t)MTOT*QKVN*2 + (size_t)NB*DIM*SEQ*2 + 65536;
    int bpp = 1;
    if (base + 4*((size_t)SEQ*SEQ*2 + SEQ*32) <= ws_size) bpp = 4;
    else if (base + 2*((size_t)SEQ*SEQ*2 + SEQ*32) <= ws_size) bpp = 2;
    float* psum = (float*)(scoresB + (size_t)bpp*SEQ*SEQ);          // [bpp][2048][8]

    // fused prep: cast x (4096 blocks) + W transposes (768) + bias (12)
    prep<<<4876, 256, 0, stream>>>(x, Wq, Wk, Wv, bq, bk, bv, xb, wqkvt, biasc);

    // fused QKV projection: grid 128x12=1536 (3.0 rounds @ 2/CU)
    // T-blocks (bn<8) -> qkv rows; V-blocks (bn>=8) -> vt transposed via LDS
    gemm4p<0><<<dim3((MTOT/64)*(QKVN/256)), 512, 0, stream>>>(
        xb, DIM, 0, wqkvt, DIM, 0, biasc, qkv, QKVN, 0, QKVN, DIM, 1.f, vt, 8);

    const float scl = 1.0f / 32.0f;   // 1/sqrt(1024)
    for (int p = 0; p < NB; p += bpp) {
        const unsigned short* qp = qkv + (size_t)p*SEQ*QKVN;
        // scores: u = exp((Q.K^T)/32) bf16 + deterministic row-sum partials -> psum
        gemm4p<2><<<dim3((SEQ/64)*(SEQ/256), bpp), 512, 0, stream>>>(
            qp,       QKVN, (size_t)SEQ*QKVN,
            qp + DIM, QKVN, (size_t)SEQ*QKVN,
            psum, scoresB, SEQ, (size_t)SEQ*SEQ, SEQ, DIM, scl, nullptr, 0);
        // PV: out[i,:] = inv[i] * (U.V)[i,:] — r14 loop, inv applied in epilogue
        gemm4p<3><<<dim3((SEQ/64)*(DIM/256), bpp), 512, 0, stream>>>(
            scoresB, SEQ, (size_t)SEQ*SEQ,
            vt + (size_t)p*DIM*SEQ, SEQ, (size_t)DIM*SEQ,
            psum, out + (size_t)p*SEQ*DIM, DIM, (size_t)SEQ*DIM, DIM, SEQ, 1.f, nullptr, 0);
    }
}

// Round 20
// 163.200 us; speedup vs baseline: 1.1813x; 1.0133x over previous
//
#include <hip/hip_runtime.h>
#include <stdint.h>

#define SEQ 2048
#define DIM 1024
#define NB 4
#define MTOT (NB*SEQ)
#define QKVN (3*DIM)

typedef __attribute__((ext_vector_type(8))) short short8;
typedef __attribute__((ext_vector_type(4))) float f32x4;

__device__ __forceinline__ unsigned short f2b(float f) {
    union { float f; unsigned int u; } v; v.f = f;
    return (unsigned short)((v.u + 0x7FFFu + ((v.u >> 16) & 1u)) >> 16);
}
__device__ __forceinline__ float b2f(unsigned short u) {
    union { unsigned int i; float f; } v; v.i = ((unsigned int)u) << 16; return v.f;
}

__device__ __forceinline__ void gload_lds16(const unsigned short* g, unsigned short* l) {
    __builtin_amdgcn_global_load_lds(
        (const __attribute__((address_space(1))) void*)g,
        (__attribute__((address_space(3))) void*)l, 16, 0, 0);
}

__device__ __forceinline__ short8 ds128(unsigned addr) {
    short8 r;
    asm volatile("ds_read_b128 %0, %1" : "=v"(r) : "v"(addr));
    return r;
}

#define FENCE_BARRIER do { asm volatile("" ::: "memory"); \
    __builtin_amdgcn_s_barrier(); asm volatile("" ::: "memory"); } while (0)
#define SB __builtin_amdgcn_sched_barrier(0)

// XCD-aware swizzle with L2-sized sub-groups: within each XCD's contiguous
// tile chunk (bm-major), reorder so ~concurrent blocks cover all chunk-bm x
// GB bn-panels (working set sized to the 4MB per-XCD L2).
__device__ __forceinline__ int xcd_swz2(int bid, int nwg, int nbn, int GB) {
    if (nwg & 7) return bid;
    int chunk = nwg >> 3;
    int xcd = bid & 7, c = bid >> 3;
    if (chunk % nbn != 0 || GB <= 0 || nbn % GB != 0)
        return xcd * chunk + c;                    // fallback: old mapping
    int rows = chunk / nbn;
    int grp = rows * GB;
    int g = c / grp, w = c % grp;
    int bm_l = w % rows, bn_l = g*GB + w / rows;
    return (xcd*rows + bm_l)*nbn + bn_l;
}

// ---------------- fused prep: cast(x) + transpose-cast(Wq,Wk,Wv) + bias ----------------
__global__ __launch_bounds__(256)
void prep(const float* __restrict__ x,
          const float* __restrict__ Wq, const float* __restrict__ Wk,
          const float* __restrict__ Wv,
          const float* __restrict__ bq, const float* __restrict__ bk,
          const float* __restrict__ bv,
          unsigned short* __restrict__ xb, unsigned short* __restrict__ wqkvt,
          float* __restrict__ biasc)
{
    __shared__ unsigned short tile[64][66];
    int b = blockIdx.x;
    int t = threadIdx.x;
    if (b < 4096) {                       // cast x -> xb (8 bf16/thread)
        int i = b*256 + t;
        float4 a = ((const float4*)x)[(size_t)i*2];
        float4 c = ((const float4*)x)[(size_t)i*2+1];
        union { unsigned short u[8]; uint4 v; } r;
        r.u[0]=f2b(a.x); r.u[1]=f2b(a.y); r.u[2]=f2b(a.z); r.u[3]=f2b(a.w);
        r.u[4]=f2b(c.x); r.u[5]=f2b(c.y); r.u[6]=f2b(c.z); r.u[7]=f2b(c.w);
        ((uint4*)xb)[i] = r.v;
        return;
    }
    if (b < 4864) {                       // transpose-cast one 64x64 tile of W
        int bb = b - 4096;
        int y = bb >> 8;                  // 0..2 selects Wq/Wk/Wv
        int bx = bb & 255;
        const float* in = (y == 0) ? Wq : (y == 1) ? Wk : Wv;
        unsigned short* o = wqkvt + (size_t)y * DIM * DIM;
        int tpc = DIM >> 6;
        int tr = (bx / tpc) << 6;
        int tc = (bx % tpc) << 6;
        #pragma unroll
        for (int i = 0; i < 16; i++) {
            int idx = t + i*256;
            int r = idx >> 6, c = idx & 63;
            tile[r][c] = f2b(in[(size_t)(tr + r)*DIM + tc + c]);
        }
        __syncthreads();
        #pragma unroll
        for (int i = 0; i < 16; i++) {
            int idx = t + i*256;
            int r = idx >> 6, c = idx & 63;
            o[(size_t)(tc + r)*DIM + tr + c] = tile[c][r];
        }
        return;
    }
    int i = (b - 4864)*256 + t;           // bias concat (3072 elems, 12 blocks)
    float v = (i < DIM) ? bq[i] : ((i < 2*DIM) ? bk[i-DIM] : bv[i-2*DIM]);
    biasc[i] = v;
}

// -------- 64x256 4-phase pipelined GEMM, 2 blocks/CU (r14 ledger, ALL modes) --------
// MODE 0: QKV — T-blocks (bn<nT): bf16(acc+aux[col]) -> C; V-blocks (bn>=nT):
//         bf16(acc+aux[col]) -> LDS-coalesced transposed write to vtout.
// MODE 2: bf16(exp(acc*scale)) + deterministic row-sum partials->aux (scores)
// MODE 3: f32(acc * inv[row]), inv from aux's 8 partials per row     (PV)
// vmcnt ledger: prologue 8 -> vmcnt(3); p1 +2; p2 +3, vmcnt(3) publish O;
// p3 +2; p4 +3, vmcnt(3) publish E2. Never 0 in loop.

__device__ __forceinline__ void stageA64(const unsigned short* __restrict__ Xb, int ldx,
                                         unsigned short* dstBase, int k0,
                                         int tid, int wid) {
    int srow = tid >> 3;
    int scol = ((tid & 7) ^ (srow & 7)) << 3;
    gload_lds16(Xb + (size_t)srow*ldx + k0 + scol, dstBase + wid*512);
}

__device__ __forceinline__ void stageB(const unsigned short* __restrict__ Xb, int ldx,
                                       unsigned short* dstBase, int h, int k0,
                                       int tid, int wid) {
    int srow = tid >> 3;
    int scol = ((tid & 7) ^ (srow & 7)) << 3;
    const unsigned short* g = Xb + (size_t)(h*128 + srow)*ldx + k0 + scol;
    unsigned short* d = dstBase + h*8192 + wid*512;
    gload_lds16(g, d);
    gload_lds16(g + (size_t)64*ldx, d + 4096);
}

#define RD_A(BUF) do { _Pragma("unroll") for (int mf = 0; mf < 2; ++mf) { \
    fa[mf][0] = ds128(As0 + (BUF)*8192u + aRow + mf*2048u + c0); \
    fa[mf][1] = ds128(As0 + (BUF)*8192u + aRow + mf*2048u + c1); } } while (0)

#define RD_B(BUF, QN) do { _Pragma("unroll") for (int nf = 0; nf < 2; ++nf) { \
    fb[nf][0] = ds128(Bs0 + (BUF)*32768u + (QN)*16384u + bRow + nf*2048u + c0); \
    fb[nf][1] = ds128(Bs0 + (BUF)*32768u + (QN)*16384u + bRow + nf*2048u + c1); } } while (0)

#define MMA_PH(QN) do { \
    asm volatile("s_waitcnt lgkmcnt(0)" ::: "memory"); \
    __builtin_amdgcn_sched_barrier(0); \
    __builtin_amdgcn_s_setprio(1); \
    _Pragma("unroll") for (int mf = 0; mf < 2; ++mf) \
      _Pragma("unroll") for (int nf = 0; nf < 2; ++nf) \
        _Pragma("unroll") for (int ks = 0; ks < 2; ++ks) \
          acc[QN][mf][nf] = __builtin_amdgcn_mfma_f32_16x16x32_bf16( \
              fa[mf][ks], fb[nf][ks], acc[QN][mf][nf], 0, 0, 0); \
    __builtin_amdgcn_s_setprio(0); \
} while (0)

template<int MODE>
__global__ __launch_bounds__(512, 2)
void gemm4p(const unsigned short* __restrict__ A, int lda, size_t sA,
            const unsigned short* __restrict__ Bt, int ldb, size_t sB,
            float* __restrict__ aux,
            void* __restrict__ Cout, int ldc, size_t sC,
            int N, int K, float scale,
            unsigned short* __restrict__ vtout, int nT, int GB)
{
    __shared__ __align__(16) unsigned short As[2][4096];     // 2 x 64x64 (16KB)
    __shared__ __align__(16) unsigned short Bs[2][16384];    // 2 x 256x64 (64KB)
    int nbn = N >> 8;
    int bid = xcd_swz2((int)blockIdx.x, (int)gridDim.x, nbn, GB);
    int bm = bid / nbn, bn = bid % nbn;
    int bz = blockIdx.y;
    int tid = threadIdx.x;
    int lane = tid & 63;
    int wid  = tid >> 6;
    int wm = (wid >> 2) & 1;
    int wn = wid & 3;
    int rlo = lane & 15;
    int shi = lane >> 4;

    unsigned As0 = (unsigned)(uintptr_t)&As[0][0];
    unsigned Bs0 = (unsigned)(uintptr_t)&Bs[0][0];
    unsigned c0 = (unsigned)(((shi     ^ rlo) & 7) * 16);
    unsigned c1 = (unsigned)((((4+shi) ^ rlo) & 7) * 16);
    unsigned aRow = (unsigned)((wm*32 + rlo) * 128);
    unsigned bRow = (unsigned)((wn*32 + rlo) * 128);

    f32x4 acc[2][2][2];
    #pragma unroll
    for (int a = 0; a < 2; a++)
        #pragma unroll
        for (int b = 0; b < 2; b++)
            #pragma unroll
            for (int c = 0; c < 2; c++)
                acc[a][b][c] = (f32x4){0.f,0.f,0.f,0.f};

    const unsigned short* Ab = A + sA*bz + (size_t)(bm*64)*lda;
    const unsigned short* Bb = Bt + sB*bz + (size_t)(bn*256)*ldb;

    // prologue: {A_E, B_E.h0, B_E.h1, A_O, B_O.h0} = 8 loads; vmcnt(3)
    stageA64(Ab, lda, &As[0][0], 0, tid, wid);
    stageB(Bb, ldb, &Bs[0][0], 0, 0,  tid, wid);
    stageB(Bb, ldb, &Bs[0][0], 1, 0,  tid, wid);
    stageA64(Ab, lda, &As[1][0], 64, tid, wid);
    stageB(Bb, ldb, &Bs[1][0], 0, 64, tid, wid);
    SB;
    asm volatile("s_waitcnt vmcnt(3)" ::: "memory");
    FENCE_BARRIER;

    short8 fa[2][2], fb[2][2];
    int nt = K >> 6;          // even, >= 4
    int nit = nt >> 1;

    for (int it = 0; it < nit; ++it) {
        int kO  = (2*it + 1) << 6;
        int kE2 = (2*it + 2 < nt) ? (2*it + 2) << 6 : 0;   // dummy k keeps ledger uniform
        int kO2 = (2*it + 3 < nt) ? (2*it + 3) << 6 : 0;

        // p1: reads A_E + B_E qn0; stage O.Bh1; pace; MFMA E qn0
        RD_A(0); RD_B(0, 0);
        stageB(Bb, ldb, &Bs[1][0], 1, kO, tid, wid);
        asm volatile("s_waitcnt lgkmcnt(4)" ::: "memory");
        FENCE_BARRIER; MMA_PH(0); FENCE_BARRIER;
        // p2: reads B_E qn1; stage E2.A + E2.Bh0; publish O; MFMA E qn1
        RD_B(0, 1);
        stageA64(Ab, lda, &As[0][0], kE2, tid, wid);
        stageB(Bb, ldb, &Bs[0][0], 0, kE2, tid, wid);
        SB;
        asm volatile("s_waitcnt vmcnt(3)" ::: "memory");
        FENCE_BARRIER; MMA_PH(1); FENCE_BARRIER;
        // p3: reads A_O + B_O qn0; stage E2.Bh1; pace; MFMA O qn0
        RD_A(1); RD_B(1, 0);
        stageB(Bb, ldb, &Bs[0][0], 1, kE2, tid, wid);
        asm volatile("s_waitcnt lgkmcnt(4)" ::: "memory");
        FENCE_BARRIER; MMA_PH(0); FENCE_BARRIER;
        // p4: reads B_O qn1; stage O2.A + O2.Bh0; publish E2; MFMA O qn1
        RD_B(1, 1);
        stageA64(Ab, lda, &As[1][0], kO2, tid, wid);
        stageB(Bb, ldb, &Bs[1][0], 0, kO2, tid, wid);
        SB;
        asm volatile("s_waitcnt vmcnt(3)" ::: "memory");
        FENCE_BARRIER; MMA_PH(1); FENCE_BARRIER;
    }

    // drain dummy-stage DMAs; barrier so LDS is quiescent before scratch reuse
    asm volatile("s_waitcnt vmcnt(0)" ::: "memory");
    FENCE_BARRIER;

    int r0 = shi << 2;
    unsigned short* Cu = (unsigned short*)Cout + sC*bz;
    float* Cf = (float*)Cout + sC*bz;

    if constexpr (MODE == 2) {
        // write u = exp(acc*scale); accumulate per-row partial sums -> aux
        float rs[2][4];
        #pragma unroll
        for (int mf = 0; mf < 2; ++mf)
            #pragma unroll
            for (int r = 0; r < 4; ++r) rs[mf][r] = 0.f;
        #pragma unroll
        for (int qn = 0; qn < 2; ++qn)
            #pragma unroll
            for (int mf = 0; mf < 2; ++mf)
                #pragma unroll
                for (int nf = 0; nf < 2; ++nf) {
                    int col = bn*256 + qn*128 + wn*32 + nf*16 + rlo;
                    #pragma unroll
                    for (int r = 0; r < 4; ++r) {
                        int row = bm*64 + wm*32 + mf*16 + r0 + r;
                        float u = __expf(acc[qn][mf][nf][r] * scale);
                        Cu[(size_t)row*ldc + col] = f2b(u);
                        rs[mf][r] += u;
                    }
                }
        #pragma unroll
        for (int m = 1; m < 16; m <<= 1)
            #pragma unroll
            for (int mf = 0; mf < 2; ++mf)
                #pragma unroll
                for (int r = 0; r < 4; ++r)
                    rs[mf][r] += __shfl_xor(rs[mf][r], m);
        float* redL = (float*)&As[0][0];   // [64][5] scratch
        if (rlo == 0) {
            #pragma unroll
            for (int mf = 0; mf < 2; ++mf)
                #pragma unroll
                for (int r = 0; r < 4; ++r)
                    redL[(wm*32 + mf*16 + (shi<<2) + r)*5 + wn] = rs[mf][r];
        }
        __syncthreads();
        if (tid < 64) {
            float s = redL[tid*5+0] + redL[tid*5+1] + redL[tid*5+2] + redL[tid*5+3];
            aux[((size_t)bz*SEQ + bm*64 + tid)*8 + bn] = s;
        }
        return;
    }

    if constexpr (MODE == 3) {
        // per-row inv from 8 psum partials (L2-hot), applied at the C-write
        float inv[2][4];
        #pragma unroll
        for (int mf = 0; mf < 2; ++mf)
            #pragma unroll
            for (int r = 0; r < 4; ++r) {
                int row = bm*64 + wm*32 + mf*16 + r0 + r;
                const float* pp = aux + ((size_t)bz*SEQ + row)*8;
                float s = pp[0]+pp[1]+pp[2]+pp[3]+pp[4]+pp[5]+pp[6]+pp[7];
                inv[mf][r] = 1.0f / s;
            }
        #pragma unroll
        for (int qn = 0; qn < 2; ++qn)
            #pragma unroll
            for (int mf = 0; mf < 2; ++mf)
                #pragma unroll
                for (int nf = 0; nf < 2; ++nf) {
                    int col = bn*256 + qn*128 + wn*32 + nf*16 + rlo;
                    #pragma unroll
                    for (int r = 0; r < 4; ++r) {
                        int row = bm*64 + wm*32 + mf*16 + r0 + r;
                        Cf[(size_t)row*ldc + col] = acc[qn][mf][nf][r] * inv[mf][r];
                    }
                }
        return;
    }

    // MODE 0: QKV with bias. T-blocks -> C rows; V-blocks -> vt via LDS transpose.
    if (bn < nT) {
        #pragma unroll
        for (int qn = 0; qn < 2; ++qn)
            #pragma unroll
            for (int mf = 0; mf < 2; ++mf)
                #pragma unroll
                for (int nf = 0; nf < 2; ++nf) {
                    int col = bn*256 + qn*128 + wn*32 + nf*16 + rlo;
                    float badd = aux[col];
                    #pragma unroll
                    for (int r = 0; r < 4; ++r) {
                        int row = bm*64 + wm*32 + mf*16 + r0 + r;
                        Cu[(size_t)row*ldc + col] = f2b(acc[qn][mf][nf][r] + badd);
                    }
                }
    } else {
        // V-part: stage [256 colv][64 sl] tile in Bs (XOR bank-swizzled),
        // then fully-coalesced 16B stores to vt[b][colv][seq].
        unsigned short* vtile = &Bs[0][0];    // 32KB, DMA-drained
        #pragma unroll
        for (int qn = 0; qn < 2; ++qn)
            #pragma unroll
            for (int mf = 0; mf < 2; ++mf)
                #pragma unroll
                for (int nf = 0; nf < 2; ++nf) {
                    int col  = bn*256 + qn*128 + wn*32 + nf*16 + rlo;
                    int colv = qn*128 + wn*32 + nf*16 + rlo;
                    float badd = aux[col];
                    int sl0 = wm*32 + mf*16 + r0;           // 4 consecutive sl
                    ushort4 w;
                    w.x = f2b(acc[qn][mf][nf][0] + badd);
                    w.y = f2b(acc[qn][mf][nf][1] + badd);
                    w.z = f2b(acc[qn][mf][nf][2] + badd);
                    w.w = f2b(acc[qn][mf][nf][3] + badd);
                    unsigned off = (unsigned)colv*128u + (((unsigned)sl0*2u) ^ (((unsigned)colv & 7u) << 4));
                    *(ushort4*)((char*)vtile + off) = w;
                }
        __syncthreads();
        int b  = (bm*64) >> 11;
        int sr = (bm*64) & 2047;
        unsigned short* vtb = vtout + (size_t)b*DIM*SEQ + (size_t)((bn - nT)*256)*SEQ + sr;
        #pragma unroll
        for (int i = 0; i < 4; ++i) {
            int cl = i*64 + (tid >> 3);                     // 0..255
            int so = (tid & 7) * 8;                         // 0..56
            unsigned off = (unsigned)cl*128u + (((unsigned)so*2u) ^ (((unsigned)cl & 7u) << 4));
            short8 vv = *(short8*)((char*)vtile + off);
            *(short8*)(vtb + (size_t)cl*SEQ + so) = vv;
        }
    }
}

extern "C" void kernel_launch(void* const* d_in, const int* in_sizes, int n_in,
                              void* d_out, int out_size, void* d_ws, size_t ws_size,
                              hipStream_t stream)
{
    (void)in_sizes; (void)n_in; (void)out_size;
    const float* x  = (const float*)d_in[0];
    const float* Wq = (const float*)d_in[1];
    const float* bq = (const float*)d_in[2];
    const float* Wk = (const float*)d_in[3];
    const float* bk = (const float*)d_in[4];
    const float* Wv = (const float*)d_in[5];
    const float* bv = (const float*)d_in[6];
    float* out = (float*)d_out;

    unsigned short* qkv = (unsigned short*)d_ws;                    // [8192][3072] (V cols unused)
    unsigned short* vt  = qkv + (size_t)MTOT*QKVN;                  // [4][1024][2048]
    float* biasc = (float*)(vt + (size_t)NB*DIM*SEQ);               // [3072]
    char* ovl = (char*)biasc + 65536;
    unsigned short* xb    = (unsigned short*)ovl;                   // [8192][1024]
    unsigned short* wqkvt = xb + (size_t)MTOT*DIM;                  // [3072][1024]
    unsigned short* scoresB = (unsigned short*)ovl;                 // [bpp][2048][2048] bf16

    size_t base = (size_t)MTOT*QKVN*2 + (size_t)NB*DIM*SEQ*2 + 65536;
    int bpp = 1;
    if (base + 4*((size_t)SEQ*SEQ*2 + SEQ*32) <= ws_size) bpp = 4;
    else if (base + 2*((size_t)SEQ*SEQ*2 + SEQ*32) <= ws_size) bpp = 2;
    float* psum = (float*)(scoresB + (size_t)bpp*SEQ*SEQ);          // [bpp][2048][8]

    // fused prep: cast x (4096 blocks) + W transposes (768) + bias (12)
    prep<<<4876, 256, 0, stream>>>(x, Wq, Wk, Wv, bq, bk, bv, xb, wqkvt, biasc);

    // fused QKV projection: grid 128x12=1536 (3.0 rounds @ 2/CU); GB=4 (A 2MB + 4
    // B-panels 2MB = 4MB per-XCD working set, fits L2)
    gemm4p<0><<<dim3((MTOT/64)*(QKVN/256)), 512, 0, stream>>>(
        xb, DIM, 0, wqkvt, DIM, 0, biasc, qkv, QKVN, 0, QKVN, DIM, 1.f, vt, 8, 4);

    const float scl = 1.0f / 32.0f;   // 1/sqrt(1024)
    for (int p = 0; p < NB; p += bpp) {
        const unsigned short* qp = qkv + (size_t)p*SEQ*QKVN;
        // scores: u = exp((Q.K^T)/32) bf16 + deterministic row-sum partials -> psum
        gemm4p<2><<<dim3((SEQ/64)*(SEQ/256), bpp), 512, 0, stream>>>(
            qp,       QKVN, (size_t)SEQ*QKVN,
            qp + DIM, QKVN, (size_t)SEQ*QKVN,
            psum, scoresB, SEQ, (size_t)SEQ*SEQ, SEQ, DIM, scl, nullptr, 0, 4);
        // PV: out[i,:] = inv[i] * (U.V)[i,:] — r14 loop, inv applied in epilogue
        gemm4p<3><<<dim3((SEQ/64)*(DIM/256), bpp), 512, 0, stream>>>(
            scoresB, SEQ, (size_t)SEQ*SEQ,
            vt + (size_t)p*DIM*SEQ, SEQ, (size_t)DIM*SEQ,
            psum, out + (size_t)p*SEQ*DIM, DIM, (size_t)SEQ*DIM, DIM, SEQ, 1.f, nullptr, 0, 2);
    }
}